// Round 1
// baseline (420.264 us; speedup 1.0000x reference)
//
#include <hip/hip_runtime.h>
#include <math.h>

// PCCNet: KNN(30) + per-neighbor MLP(6->64->64) + 3-scale prefix softmax attention.
// Inputs (all f32): x(8,3,4096) w1(64,6) g1(64) b1(64) w2(64,64) g2(64) b2(64)
//                   wa(1,64) ba(1) ga(1) bga(1)
// Output f32 (8,64,4096). Workspace: knn indices int32 [32768][32] = 4 MB.

#define NB 8
#define NPT 4096
#define KMAXK 30
#define ROWS (NB * NPT)

__device__ __forceinline__ unsigned long long shflx64(unsigned long long v, int m) {
  unsigned lo = (unsigned)__shfl_xor((int)(unsigned)(v & 0xFFFFFFFFull), m, 64);
  unsigned hi = (unsigned)__shfl_xor((int)(unsigned)(v >> 32), m, 64);
  return ((unsigned long long)hi << 32) | (unsigned long long)lo;
}

__device__ __forceinline__ float bcastlane(float v, int l) {
  return __int_as_float(__builtin_amdgcn_readlane(__float_as_int(v), l));
}

// ---------------- Kernel 1: exact top-30 neighbor indices per point --------
// One wave per row (b,n). Each lane owns 64 candidates m = lane + 64*j.
// pd = 2*inner - xx_n - xx_m  (<=0 except tiny fp noise; diag exactly 0).
// Monotonic u32 key; tie-break lower index first via packed (key<<32)|(4095-m).
__global__ __launch_bounds__(256) void knn_kernel(const float* __restrict__ x,
                                                  int* __restrict__ knn) {
  __shared__ unsigned long long buf[4][1024];
  const int wv = threadIdx.x >> 6;
  const int lane = threadIdx.x & 63;
  const int row = (blockIdx.x << 2) + wv;
  const int b = row >> 12;
  const int n = row & (NPT - 1);
  const float* xb = x + (size_t)b * 3 * NPT;

  const float xn0 = xb[n], xn1 = xb[NPT + n], xn2 = xb[2 * NPT + n];
  const float xxn = xn0 * xn0 + xn1 * xn1 + xn2 * xn2;

  unsigned keys[64];
  unsigned kmax = 0u;
#pragma unroll
  for (int j = 0; j < 64; ++j) {
    const int m = (j << 6) + lane;
    const float y0 = xb[m], y1 = xb[NPT + m], y2 = xb[2 * NPT + m];
    const float inner = y0 * xn0 + y1 * xn1 + y2 * xn2;
    const float xxm = y0 * y0 + y1 * y1 + y2 * y2;
    const float pd = 2.0f * inner - xxn - xxm;
    const unsigned bits = __float_as_uint(pd);
    const unsigned key = (bits & 0x80000000u) ? ~bits : (bits | 0x80000000u);
    keys[j] = key;
    kmax = key > kmax ? key : kmax;
  }

  // Ascending bitonic sort of the 64 lane-maxima across lanes.
  unsigned v = kmax;
#pragma unroll
  for (int kk = 2; kk <= 64; kk <<= 1) {
#pragma unroll
    for (int jj = 32; jj >= 1; jj >>= 1) {
      if (jj < kk) {
        const unsigned o = (unsigned)__shfl_xor((int)v, jj, 64);
        const bool up = ((lane & kk) == 0);
        const bool takeMax = (((lane & jj) != 0) == up);
        const unsigned mx = v > o ? v : o;
        const unsigned mn = v > o ? o : v;
        v = takeMax ? mx : mn;
      }
    }
  }
  // 30th-largest lane max: guaranteed <= true 30th-largest overall value,
  // and guaranteed >= 30 elements pass it.
  const unsigned t = (unsigned)__shfl((int)v, 34, 64);

  unsigned long long* mybuf = buf[wv];
  int cnt = 0;
#pragma unroll
  for (int j = 0; j < 64; ++j) {
    const bool pred = keys[j] >= t;
    const unsigned long long mask = __ballot(pred);
    if (pred) {
      const int pos = cnt + (int)__popcll(mask & ((1ull << lane) - 1ull));
      if (pos < 1024) {
        const int m = (j << 6) + lane;
        mybuf[pos] = ((unsigned long long)keys[j] << 32) | (unsigned)(4095 - m);
      }
    }
    cnt += (int)__popcll(mask);
  }

  const int outbase = row * 32;
  if (cnt <= 64) {
    // Typical path (expected cnt ~ 48): full 64-lane bitonic sort, ascending.
    unsigned long long val = (lane < cnt) ? mybuf[lane] : 0ull;
#pragma unroll
    for (int kk = 2; kk <= 64; kk <<= 1) {
#pragma unroll
      for (int jj = 32; jj >= 1; jj >>= 1) {
        if (jj < kk) {
          const unsigned long long o = shflx64(val, jj);
          const bool up = ((lane & kk) == 0);
          const bool takeMax = (((lane & jj) != 0) == up);
          const unsigned long long mx = val > o ? val : o;
          const unsigned long long mn = val > o ? o : val;
          val = takeMax ? mx : mn;
        }
      }
    }
    const int rank = 63 - lane;  // lane 63 holds the largest
    if (rank < KMAXK) {
      const int m = 4095 - (int)(val & 0xFFFFFFFFull);
      knn[outbase + rank] = m;
    }
  } else {
    // Rare path: iterative wave-argmax (exact, handles up to 1024 survivors).
    const int cc = cnt < 1024 ? cnt : 1024;
    for (int r = 0; r < KMAXK; ++r) {
      unsigned long long lmax = 0ull;
      int lpos = -1;
      for (int p = lane; p < cc; p += 64) {
        const unsigned long long q = mybuf[p];
        if (q > lmax) { lmax = q; lpos = p; }
      }
      unsigned long long g = lmax;
#pragma unroll
      for (int s = 32; s >= 1; s >>= 1) {
        const unsigned long long o = shflx64(g, s);
        g = o > g ? o : g;
      }
      // packed keys are unique (index field) -> exactly one winner lane
      const unsigned long long pm = __ballot(lmax == g && lpos >= 0);
      const int lowlane = (int)(__ffsll((unsigned long long)pm) - 1);
      if (lane == lowlane) mybuf[lpos] = 0ull;
      if (lane == 0) knn[outbase + r] = 4095 - (int)(g & 0xFFFFFFFFull);
    }
  }
}

// ---------------- Kernel 2: MLP + 3-scale softmax attention ----------------
// One wave per row; lane = output channel o (0..63).
__global__ __launch_bounds__(256) void pcc_mlp_kernel(
    const float* __restrict__ x, const float* __restrict__ w1,
    const float* __restrict__ g1, const float* __restrict__ b1,
    const float* __restrict__ w2, const float* __restrict__ g2,
    const float* __restrict__ b2, const float* __restrict__ wa,
    const float* __restrict__ ba, const float* __restrict__ ga,
    const float* __restrict__ bga, const int* __restrict__ knn,
    float* __restrict__ out) {
  const int wv = threadIdx.x >> 6;
  const int lane = threadIdx.x & 63;
  const int row = (blockIdx.x << 2) + wv;
  const int b = row >> 12;
  const int n = row & (NPT - 1);
  const float* xb = x + (size_t)b * 3 * NPT;

  const float invs = 1.0f / sqrtf(1.0f + 1e-5f);
  const float s1 = g1[lane] * invs, be1 = b1[lane];
  const float s2 = g2[lane] * invs, be2 = b2[lane];
  const float wao = wa[lane];
  const float sa = ga[0] * invs, ba0 = ba[0], bga0 = bga[0];

  float w1r[6];
#pragma unroll
  for (int i = 0; i < 6; ++i) w1r[i] = w1[lane * 6 + i];
  float w2r[64];
#pragma unroll
  for (int i = 0; i < 64; ++i) w2r[i] = w2[lane * 64 + i];

  const float xn0 = xb[n], xn1 = xb[NPT + n], xn2 = xb[2 * NPT + n];

  // Lanes 0..29 preload their neighbor's coordinates.
  float nb0 = 0.f, nb1 = 0.f, nb2 = 0.f;
  if (lane < KMAXK) {
    const int mj = knn[row * 32 + lane];
    nb0 = xb[mj];
    nb1 = xb[NPT + mj];
    nb2 = xb[2 * NPT + mj];
  }

  float h2r[KMAXK];
  float amine = 0.f;
#pragma unroll
  for (int j = 0; j < KMAXK; ++j) {
    const float d0 = bcastlane(nb0, j) - xn0;
    const float d1 = bcastlane(nb1, j) - xn1;
    const float d2 = bcastlane(nb2, j) - xn2;
    // layer 1: 6 -> 64, BN(eval) + leaky relu.  f = [dx,dy,dz, cx,cy,cz]
    float h = w1r[0] * d0;
    h = fmaf(w1r[1], d1, h);
    h = fmaf(w1r[2], d2, h);
    h = fmaf(w1r[3], xn0, h);
    h = fmaf(w1r[4], xn1, h);
    h = fmaf(w1r[5], xn2, h);
    h = fmaf(h, s1, be1);
    h = fmaxf(h, 0.2f * h);  // leaky relu (works for both signs)
    // layer 2: 64 -> 64 via readlane broadcast; 4 accumulators break FMA chain
    float a0 = 0.f, a1 = 0.f, a2 = 0.f, a3 = 0.f;
#pragma unroll
    for (int i = 0; i < 64; i += 4) {
      a0 = fmaf(w2r[i + 0], bcastlane(h, i + 0), a0);
      a1 = fmaf(w2r[i + 1], bcastlane(h, i + 1), a1);
      a2 = fmaf(w2r[i + 2], bcastlane(h, i + 2), a2);
      a3 = fmaf(w2r[i + 3], bcastlane(h, i + 3), a3);
    }
    float h2 = fmaf((a0 + a1) + (a2 + a3), s2, be2);
    h2 = fmaxf(h2, 0.2f * h2);
    h2r[j] = h2;
    // attention scalar: wa . h2 (+ba), BN, lrelu — butterfly sum over lanes
    float r = wao * h2;
#pragma unroll
    for (int s = 32; s >= 1; s >>= 1) r += __shfl_xor(r, s, 64);
    float aj = fmaf(r + ba0, sa, bga0);
    aj = fmaxf(aj, 0.2f * aj);
    amine = (lane == j) ? aj : amine;  // lane j keeps score of neighbor j
  }

  // Three prefix softmaxes (k = 10, 20, 30); lane j accumulates its weight.
  float wsum = 0.f;
#pragma unroll
  for (int t3 = 1; t3 <= 3; ++t3) {
    const int kk = 10 * t3;
    float av = (lane < kk) ? amine : -3.0e38f;
#pragma unroll
    for (int s = 32; s >= 1; s >>= 1) av = fmaxf(av, __shfl_xor(av, s, 64));
    const float e = (lane < kk) ? expf(amine - av) : 0.f;
    float ssum = e;
#pragma unroll
    for (int s = 32; s >= 1; s >>= 1) ssum += __shfl_xor(ssum, s, 64);
    wsum += e / ssum;
  }
  wsum *= (1.0f / 3.0f);

  // out[b, lane, n] = sum_j wsum_j * h2[j, lane]
  float acc = 0.f;
#pragma unroll
  for (int j = 0; j < KMAXK; ++j) {
    acc = fmaf(bcastlane(wsum, j), h2r[j], acc);
  }
  out[(size_t)(b * 64 + lane) * NPT + n] = acc;
}

extern "C" void kernel_launch(void* const* d_in, const int* in_sizes, int n_in,
                              void* d_out, int out_size, void* d_ws, size_t ws_size,
                              hipStream_t stream) {
  const float* x = (const float*)d_in[0];
  const float* w1 = (const float*)d_in[1];
  const float* g1 = (const float*)d_in[2];
  const float* b1 = (const float*)d_in[3];
  const float* w2 = (const float*)d_in[4];
  const float* g2 = (const float*)d_in[5];
  const float* b2 = (const float*)d_in[6];
  const float* wa = (const float*)d_in[7];
  const float* ba = (const float*)d_in[8];
  const float* ga = (const float*)d_in[9];
  const float* bga = (const float*)d_in[10];
  float* out = (float*)d_out;
  int* knn = (int*)d_ws;  // [ROWS][32] ints = 4 MB

  knn_kernel<<<dim3(ROWS / 4), dim3(256), 0, stream>>>(x, knn);
  pcc_mlp_kernel<<<dim3(ROWS / 4), dim3(256), 0, stream>>>(
      x, w1, g1, b1, w2, g2, b2, wa, ba, ga, bga, knn, out);
}

// Round 2
// 229.431 us; speedup vs baseline: 1.8318x; 1.8318x over previous
//
#include <hip/hip_runtime.h>
#include <math.h>

// PCCNet: KNN(30) + per-neighbor MLP(6->64->64) + 3-scale prefix softmax attention.
// Round 2: layer-2 (64x64 over 30 neighbors) moved to bf16 MFMA, one wave/point.

#define NB 8
#define NPT 4096
#define KMAXK 30
#define ROWS (NB * NPT)

typedef __attribute__((ext_vector_type(8))) short short8v;
typedef __attribute__((ext_vector_type(4))) float float4v;

__device__ __forceinline__ unsigned long long shflx64(unsigned long long v, int m) {
  unsigned lo = (unsigned)__shfl_xor((int)(unsigned)(v & 0xFFFFFFFFull), m, 64);
  unsigned hi = (unsigned)__shfl_xor((int)(unsigned)(v >> 32), m, 64);
  return ((unsigned long long)hi << 32) | (unsigned long long)lo;
}

__device__ __forceinline__ short f2bf(float x) {  // f32 -> bf16 RNE
  unsigned u = __float_as_uint(x);
  return (short)((u + 0x7FFFu + ((u >> 16) & 1u)) >> 16);
}

// ---------------- Kernel 1: exact top-30 neighbor indices per point --------
// (unchanged from round 1 — passed exactness; ~100us, optimize next round)
__global__ __launch_bounds__(256) void knn_kernel(const float* __restrict__ x,
                                                  int* __restrict__ knn) {
  __shared__ unsigned long long buf[4][1024];
  const int wv = threadIdx.x >> 6;
  const int lane = threadIdx.x & 63;
  const int row = (blockIdx.x << 2) + wv;
  const int b = row >> 12;
  const int n = row & (NPT - 1);
  const float* xb = x + (size_t)b * 3 * NPT;

  const float xn0 = xb[n], xn1 = xb[NPT + n], xn2 = xb[2 * NPT + n];
  const float xxn = xn0 * xn0 + xn1 * xn1 + xn2 * xn2;

  unsigned keys[64];
  unsigned kmax = 0u;
#pragma unroll
  for (int j = 0; j < 64; ++j) {
    const int m = (j << 6) + lane;
    const float y0 = xb[m], y1 = xb[NPT + m], y2 = xb[2 * NPT + m];
    const float inner = y0 * xn0 + y1 * xn1 + y2 * xn2;
    const float xxm = y0 * y0 + y1 * y1 + y2 * y2;
    const float pd = 2.0f * inner - xxn - xxm;
    const unsigned bits = __float_as_uint(pd);
    const unsigned key = (bits & 0x80000000u) ? ~bits : (bits | 0x80000000u);
    keys[j] = key;
    kmax = key > kmax ? key : kmax;
  }

  unsigned v = kmax;
#pragma unroll
  for (int kk = 2; kk <= 64; kk <<= 1) {
#pragma unroll
    for (int jj = 32; jj >= 1; jj >>= 1) {
      if (jj < kk) {
        const unsigned o = (unsigned)__shfl_xor((int)v, jj, 64);
        const bool up = ((lane & kk) == 0);
        const bool takeMax = (((lane & jj) != 0) == up);
        const unsigned mx = v > o ? v : o;
        const unsigned mn = v > o ? o : v;
        v = takeMax ? mx : mn;
      }
    }
  }
  const unsigned t = (unsigned)__shfl((int)v, 34, 64);

  unsigned long long* mybuf = buf[wv];
  int cnt = 0;
#pragma unroll
  for (int j = 0; j < 64; ++j) {
    const bool pred = keys[j] >= t;
    const unsigned long long mask = __ballot(pred);
    if (pred) {
      const int pos = cnt + (int)__popcll(mask & ((1ull << lane) - 1ull));
      if (pos < 1024) {
        const int m = (j << 6) + lane;
        mybuf[pos] = ((unsigned long long)keys[j] << 32) | (unsigned)(4095 - m);
      }
    }
    cnt += (int)__popcll(mask);
  }

  const int outbase = row * 32;
  if (cnt <= 64) {
    unsigned long long val = (lane < cnt) ? mybuf[lane] : 0ull;
#pragma unroll
    for (int kk = 2; kk <= 64; kk <<= 1) {
#pragma unroll
      for (int jj = 32; jj >= 1; jj >>= 1) {
        if (jj < kk) {
          const unsigned long long o = shflx64(val, jj);
          const bool up = ((lane & kk) == 0);
          const bool takeMax = (((lane & jj) != 0) == up);
          const unsigned long long mx = val > o ? val : o;
          const unsigned long long mn = val > o ? o : val;
          val = takeMax ? mx : mn;
        }
      }
    }
    const int rank = 63 - lane;
    if (rank < KMAXK) {
      const int m = 4095 - (int)(val & 0xFFFFFFFFull);
      knn[outbase + rank] = m;
    }
  } else {
    const int cc = cnt < 1024 ? cnt : 1024;
    for (int r = 0; r < KMAXK; ++r) {
      unsigned long long lmax = 0ull;
      int lpos = -1;
      for (int p = lane; p < cc; p += 64) {
        const unsigned long long q = mybuf[p];
        if (q > lmax) { lmax = q; lpos = p; }
      }
      unsigned long long g = lmax;
#pragma unroll
      for (int s = 32; s >= 1; s >>= 1) {
        const unsigned long long o = shflx64(g, s);
        g = o > g ? o : g;
      }
      const unsigned long long pm = __ballot(lmax == g && lpos >= 0);
      const int lowlane = (int)(__ffsll((unsigned long long)pm) - 1);
      if (lane == lowlane) mybuf[lpos] = 0ull;
      if (lane == 0) knn[outbase + r] = 4095 - (int)(g & 0xFFFFFFFFull);
    }
  }
}

// ---------------- Kernel 2: MFMA MLP + 3-scale softmax attention -----------
// One wave per point. A = h1 (32 rows: 30 neighbors + 2 pad, K=64 channels),
// B = W2^T. Chosen k-permutation k(g,e)=kt*32+g*8+e applied identically to A
// and B packing, so only row/col = lane&15 symmetry of the HW layout matters.
// C/D layout (HW-verified): n = lane&15, m = (lane>>4)*4 + reg.
__global__ __launch_bounds__(256) void pcc_mlp_mfma(
    const float* __restrict__ x, const float* __restrict__ w1,
    const float* __restrict__ g1, const float* __restrict__ b1,
    const float* __restrict__ w2, const float* __restrict__ g2,
    const float* __restrict__ b2, const float* __restrict__ wa,
    const float* __restrict__ ba, const float* __restrict__ ga,
    const float* __restrict__ bga, const int* __restrict__ knn,
    float* __restrict__ out) {
  __shared__ float w1row[64][8];  // per channel: w1[0..5], s1, be1  (2 KB)
  const int tid = threadIdx.x;
  const float invs = 1.0f / sqrtf(1.0f + 1e-5f);
  for (int idx = tid; idx < 512; idx += 256) {
    const int c = idx >> 3, s = idx & 7;
    float v;
    if (s < 6) v = w1[c * 6 + s];
    else if (s == 6) v = g1[c] * invs;
    else v = b1[c];
    w1row[c][s] = v;
  }
  __syncthreads();

  const int wv = tid >> 6, lane = tid & 63;
  const int q = lane & 15, g = lane >> 4;
  const int row = (blockIdx.x << 2) + wv;
  const int b = row >> 12, n = row & (NPT - 1);
  const float* xb = x + (size_t)b * 3 * NPT;

  // B fragments: bf[kt][nt] elem e = B[k=kt*32+g*8+e][n=nt*16+q] = w2[n][k]
  short8v bf[2][4];
#pragma unroll
  for (int kt = 0; kt < 2; ++kt)
#pragma unroll
    for (int nt = 0; nt < 4; ++nt) {
      const float* src = w2 + (nt * 16 + q) * 64 + kt * 32 + g * 8;
      const float4v lo = *(const float4v*)(src);
      const float4v hi = *(const float4v*)(src + 4);
      short8v t;
#pragma unroll
      for (int e = 0; e < 4; ++e) t[e] = f2bf(lo[e]);
#pragma unroll
      for (int e = 0; e < 4; ++e) t[4 + e] = f2bf(hi[e]);
      bf[kt][nt] = t;
    }

  // per-lane epilogue constants for channels o = q + 16*nt
  float s2r[4], be2r[4], war[4];
#pragma unroll
  for (int nt = 0; nt < 4; ++nt) {
    s2r[nt] = g2[q + 16 * nt] * invs;
    be2r[nt] = b2[q + 16 * nt];
    war[nt] = wa[q + 16 * nt];
  }
  const float sa = ga[0] * invs, ba0 = ba[0], bga0 = bga[0];

  const float xn0 = xb[n], xn1 = xb[NPT + n], xn2 = xb[2 * NPT + n];

  // neighbor coords for A rows m=q (j=q) and m=16+q (j=16+q, valid iff q<14)
  const int j0 = knn[row * 32 + q];
  const float a0x = xb[j0], a0y = xb[NPT + j0], a0z = xb[2 * NPT + j0];
  float a1x = xn0, a1y = xn1, a1z = xn2;  // pad: d=0, finite
  if (q < 14) {
    const int j1 = knn[row * 32 + 16 + q];
    a1x = xb[j1]; a1y = xb[NPT + j1]; a1z = xb[2 * NPT + j1];
  }
  const float d0x = a0x - xn0, d0y = a0y - xn1, d0z = a0z - xn2;
  const float d1x = a1x - xn0, d1y = a1y - xn1, d1z = a1z - xn2;

  // layer 1 (VALU, from LDS consts) -> A fragments -> MFMA layer 2
  float4v dfr[2][4];
#pragma unroll
  for (int mt = 0; mt < 2; ++mt)
#pragma unroll
    for (int nt = 0; nt < 4; ++nt) dfr[mt][nt] = (float4v){0.f, 0.f, 0.f, 0.f};

#pragma unroll
  for (int kt = 0; kt < 2; ++kt) {
    short8v af0, af1;
#pragma unroll
    for (int e = 0; e < 8; ++e) {
      const int c = kt * 32 + g * 8 + e;
      const float4v wlo = *(const float4v*)&w1row[c][0];
      const float4v whi = *(const float4v*)&w1row[c][4];
      float h = wlo[0] * d0x;
      h = fmaf(wlo[1], d0y, h);
      h = fmaf(wlo[2], d0z, h);
      h = fmaf(wlo[3], xn0, h);
      h = fmaf(whi[0], xn1, h);
      h = fmaf(whi[1], xn2, h);
      h = fmaf(h, whi[2], whi[3]);
      h = fmaxf(h, 0.2f * h);
      af0[e] = f2bf(h);
      float h1v = wlo[0] * d1x;
      h1v = fmaf(wlo[1], d1y, h1v);
      h1v = fmaf(wlo[2], d1z, h1v);
      h1v = fmaf(wlo[3], xn0, h1v);
      h1v = fmaf(whi[0], xn1, h1v);
      h1v = fmaf(whi[1], xn2, h1v);
      h1v = fmaf(h1v, whi[2], whi[3]);
      h1v = fmaxf(h1v, 0.2f * h1v);
      af1[e] = f2bf(h1v);
    }
#pragma unroll
    for (int nt = 0; nt < 4; ++nt) {
      dfr[0][nt] = __builtin_amdgcn_mfma_f32_16x16x32_bf16(af0, bf[kt][nt], dfr[0][nt], 0, 0, 0);
      dfr[1][nt] = __builtin_amdgcn_mfma_f32_16x16x32_bf16(af1, bf[kt][nt], dfr[1][nt], 0, 0, 0);
    }
  }

  // BN2 + leaky relu in C layout; attention partial dot over this lane's 4 chans
  float part[2][4];
#pragma unroll
  for (int mt = 0; mt < 2; ++mt)
#pragma unroll
    for (int r = 0; r < 4; ++r) part[mt][r] = 0.f;
#pragma unroll
  for (int mt = 0; mt < 2; ++mt)
#pragma unroll
    for (int nt = 0; nt < 4; ++nt) {
      float4v d = dfr[mt][nt];
#pragma unroll
      for (int r = 0; r < 4; ++r) {
        float h2 = fmaf(d[r], s2r[nt], be2r[nt]);
        h2 = fmaxf(h2, 0.2f * h2);
        d[r] = h2;
        part[mt][r] = fmaf(war[nt], h2, part[mt][r]);
      }
      dfr[mt][nt] = d;
    }
  // sum over the 16 q-lanes (full 64-channel dot)
#pragma unroll
  for (int mt = 0; mt < 2; ++mt)
#pragma unroll
    for (int r = 0; r < 4; ++r) {
      float p = part[mt][r];
      p += __shfl_xor(p, 1, 64);
      p += __shfl_xor(p, 2, 64);
      p += __shfl_xor(p, 4, 64);
      p += __shfl_xor(p, 8, 64);
      part[mt][r] = p;
    }

  // scores; this lane owns rows m = g*4 + r (+16*mt) -> neighbor j
  const int mrow = g * 4;
  float sc0[4], sc1[4];
  float mloc = -3.0e38f;
#pragma unroll
  for (int r = 0; r < 4; ++r) {
    float a = fmaf(part[0][r] + ba0, sa, bga0);
    a = fmaxf(a, 0.2f * a);
    sc0[r] = a;
    mloc = fmaxf(mloc, a);
  }
#pragma unroll
  for (int r = 0; r < 4; ++r) {
    float a = fmaf(part[1][r] + ba0, sa, bga0);
    a = fmaxf(a, 0.2f * a);
    sc1[r] = a;
    if (mrow + r < 14) mloc = fmaxf(mloc, a);  // j = 16+mrow+r < 30
  }
  mloc = fmaxf(mloc, __shfl_xor(mloc, 16, 64));
  mloc = fmaxf(mloc, __shfl_xor(mloc, 32, 64));

  float e0[4], e1[4];
  float l10 = 0.f, l20 = 0.f, l30 = 0.f;
#pragma unroll
  for (int r = 0; r < 4; ++r) {
    const float v = expf(sc0[r] - mloc);
    e0[r] = v;
    l30 += v;
    l20 += v;
    if (mrow + r < 10) l10 += v;
  }
#pragma unroll
  for (int r = 0; r < 4; ++r) {
    const float v = (mrow + r < 14) ? expf(sc1[r] - mloc) : 0.f;
    e1[r] = v;
    l30 += v;
    if (mrow + r < 4) l20 += v;  // j = 16+mrow+r < 20
  }
  l10 += __shfl_xor(l10, 16, 64); l10 += __shfl_xor(l10, 32, 64);
  l20 += __shfl_xor(l20, 16, 64); l20 += __shfl_xor(l20, 32, 64);
  l30 += __shfl_xor(l30, 16, 64); l30 += __shfl_xor(l30, 32, 64);
  const float i10 = 1.0f / l10, i20 = 1.0f / l20, i30 = 1.0f / l30;
  const float third = 1.0f / 3.0f;

  float wgt0[4], wgt1[4];
#pragma unroll
  for (int r = 0; r < 4; ++r) {
    wgt0[r] = e0[r] * (((mrow + r < 10) ? i10 : 0.f) + i20 + i30) * third;
    wgt1[r] = e1[r] * (((mrow + r < 4) ? i20 : 0.f) + i30) * third;
  }

  // weighted sum of h2 over neighbors
  float acc[4] = {0.f, 0.f, 0.f, 0.f};
#pragma unroll
  for (int nt = 0; nt < 4; ++nt) {
#pragma unroll
    for (int r = 0; r < 4; ++r) {
      acc[nt] = fmaf(wgt0[r], dfr[0][nt][r], acc[nt]);
      acc[nt] = fmaf(wgt1[r], dfr[1][nt][r], acc[nt]);
    }
  }
#pragma unroll
  for (int nt = 0; nt < 4; ++nt) {
    acc[nt] += __shfl_xor(acc[nt], 16, 64);
    acc[nt] += __shfl_xor(acc[nt], 32, 64);
  }
  const float val = (g == 0) ? acc[0] : (g == 1) ? acc[1] : (g == 2) ? acc[2] : acc[3];
  out[(size_t)(b * 64 + q + 16 * g) * NPT + n] = val;
}

extern "C" void kernel_launch(void* const* d_in, const int* in_sizes, int n_in,
                              void* d_out, int out_size, void* d_ws, size_t ws_size,
                              hipStream_t stream) {
  const float* x = (const float*)d_in[0];
  const float* w1 = (const float*)d_in[1];
  const float* g1 = (const float*)d_in[2];
  const float* b1 = (const float*)d_in[3];
  const float* w2 = (const float*)d_in[4];
  const float* g2 = (const float*)d_in[5];
  const float* b2 = (const float*)d_in[6];
  const float* wa = (const float*)d_in[7];
  const float* ba = (const float*)d_in[8];
  const float* ga = (const float*)d_in[9];
  const float* bga = (const float*)d_in[10];
  float* out = (float*)d_out;
  int* knn = (int*)d_ws;  // [ROWS][32] ints = 4 MB

  knn_kernel<<<dim3(ROWS / 4), dim3(256), 0, stream>>>(x, knn);
  pcc_mlp_mfma<<<dim3(ROWS / 4), dim3(256), 0, stream>>>(
      x, w1, g1, b1, w2, g2, b2, wa, ba, ga, bga, knn, out);
}

// Round 3
// 217.199 us; speedup vs baseline: 1.9349x; 1.0563x over previous
//
#include <hip/hip_runtime.h>
#include <math.h>

// PCCNet: KNN(30) + per-neighbor MLP(6->64->64) + 3-scale prefix softmax attention.
// Round 3: knn distance loop on packed float4 (x,y,z,|x|^2) table, float-domain
// threshold, 8KB LDS, launch_bounds occupancy. MLP kernel numerics unchanged.

#define NB 8
#define NPT 4096
#define KMAXK 30
#define ROWS (NB * NPT)
#define SCAP 256  // survivor cap per wave (observed ~48 on this data)

typedef __attribute__((ext_vector_type(8))) short short8v;
typedef __attribute__((ext_vector_type(4))) float float4v;

__device__ __forceinline__ unsigned long long shflx64(unsigned long long v, int m) {
  unsigned lo = (unsigned)__shfl_xor((int)(unsigned)(v & 0xFFFFFFFFull), m, 64);
  unsigned hi = (unsigned)__shfl_xor((int)(unsigned)(v >> 32), m, 64);
  return ((unsigned long long)hi << 32) | (unsigned long long)lo;
}

__device__ __forceinline__ short f2bf(float x) {  // f32 -> bf16 RNE
  unsigned u = __float_as_uint(x);
  return (short)((u + 0x7FFFu + ((u >> 16) & 1u)) >> 16);
}

__device__ __forceinline__ unsigned ordkey(float f) {  // monotonic u32 of f32
  const unsigned bits = __float_as_uint(f);
  return bits ^ ((unsigned)((int)bits >> 31) | 0x80000000u);
}

// ---------------- Kernel 0: pack (x,y,z,|x|^2) per point -------------------
// Same |x|^2 expression as the original in-kernel computation (rounding-stable).
__global__ __launch_bounds__(256) void prep_kernel(const float* __restrict__ x,
                                                   float4v* __restrict__ xq) {
  const int i = blockIdx.x * 256 + threadIdx.x;  // 0..ROWS-1
  const int b = i >> 12, m = i & (NPT - 1);
  const float* xb = x + (size_t)b * 3 * NPT;
  const float y0 = xb[m], y1 = xb[NPT + m], y2 = xb[2 * NPT + m];
  const float xx = y0 * y0 + y1 * y1 + y2 * y2;
  xq[i] = (float4v){y0, y1, y2, xx};
}

// ---------------- Kernel 1: exact top-30 neighbor indices per point --------
// One wave per row (b,n). Each lane owns 64 candidates m = lane + 64*j.
// pd = 2*inner - xx_n - xx_m (same op order as before). Threshold t = 30th
// largest lane-max (float domain). Survivors packed (ordkey<<32)|(4095-m),
// 64-lane bitonic sort -> exact descending top-30 with lower-index tie-break.
__global__ __launch_bounds__(256, 6) void knn_kernel(const float4v* __restrict__ xq,
                                                     int* __restrict__ knn) {
  __shared__ unsigned long long buf[4][SCAP];
  const int wv = threadIdx.x >> 6;
  const int lane = threadIdx.x & 63;
  const int row = (blockIdx.x << 2) + wv;
  const int b = row >> 12;
  const int n = row & (NPT - 1);
  const float4v* xqb = xq + ((size_t)b << 12);

  const float4v qv = xqb[n];
  const float xn0 = qv[0], xn1 = qv[1], xn2 = qv[2], xxn = qv[3];

  float keys[64];
  float kmax = -3.0e38f;
#pragma unroll
  for (int j = 0; j < 64; ++j) {
    const int m = (j << 6) + lane;
    const float4v c = xqb[m];
    const float inner = c[0] * xn0 + c[1] * xn1 + c[2] * xn2;
    const float pd = 2.0f * inner - xxn - c[3];
    keys[j] = pd;
    kmax = fmaxf(kmax, pd);
  }

  // Ascending bitonic sort of the 64 lane-maxima (floats, no NaN possible).
  float v = kmax;
#pragma unroll
  for (int kk = 2; kk <= 64; kk <<= 1) {
#pragma unroll
    for (int jj = 32; jj >= 1; jj >>= 1) {
      if (jj < kk) {
        const float o = __shfl_xor(v, jj, 64);
        const bool up = ((lane & kk) == 0);
        const bool takeMax = (((lane & jj) != 0) == up);
        v = takeMax ? fmaxf(v, o) : fminf(v, o);
      }
    }
  }
  // 30th-largest lane max: <= true 30th value overall, >= 30 elements pass.
  const float t = __shfl(v, 34, 64);

  unsigned long long* mybuf = buf[wv];
  int cnt = 0;
#pragma unroll
  for (int j = 0; j < 64; ++j) {
    const bool pred = keys[j] >= t;
    const unsigned long long mask = __ballot(pred);
    if (pred) {
      const int pos = cnt + (int)__popcll(mask & ((1ull << lane) - 1ull));
      if (pos < SCAP) {
        const int m = (j << 6) + lane;
        mybuf[pos] = ((unsigned long long)ordkey(keys[j]) << 32) | (unsigned)(4095 - m);
      }
    }
    cnt += (int)__popcll(mask);
  }

  const int outbase = row * 32;
  if (cnt <= 64) {
    // Typical path (~48 survivors): full 64-lane bitonic sort, ascending.
    unsigned long long val = (lane < cnt) ? mybuf[lane] : 0ull;
#pragma unroll
    for (int kk = 2; kk <= 64; kk <<= 1) {
#pragma unroll
      for (int jj = 32; jj >= 1; jj >>= 1) {
        if (jj < kk) {
          const unsigned long long o = shflx64(val, jj);
          const bool up = ((lane & kk) == 0);
          const bool takeMax = (((lane & jj) != 0) == up);
          const unsigned long long mx = val > o ? val : o;
          const unsigned long long mn = val > o ? o : val;
          val = takeMax ? mx : mn;
        }
      }
    }
    const int rank = 63 - lane;  // lane 63 holds the largest
    if (rank < KMAXK) {
      const int m = 4095 - (int)(val & 0xFFFFFFFFull);
      knn[outbase + rank] = m;
    }
  } else {
    // Rare path: iterative wave-argmax (exact up to SCAP survivors).
    const int cc = cnt < SCAP ? cnt : SCAP;
    for (int r = 0; r < KMAXK; ++r) {
      unsigned long long lmax = 0ull;
      int lpos = -1;
      for (int p = lane; p < cc; p += 64) {
        const unsigned long long q = mybuf[p];
        if (q > lmax) { lmax = q; lpos = p; }
      }
      unsigned long long g = lmax;
#pragma unroll
      for (int s = 32; s >= 1; s >>= 1) {
        const unsigned long long o = shflx64(g, s);
        g = o > g ? o : g;
      }
      const unsigned long long pm = __ballot(lmax == g && lpos >= 0);
      const int lowlane = (int)(__ffsll((unsigned long long)pm) - 1);
      if (lane == lowlane) mybuf[lpos] = 0ull;
      if (lane == 0) knn[outbase + r] = 4095 - (int)(g & 0xFFFFFFFFull);
    }
  }
}

// ---------------- Kernel 2: MFMA MLP + 3-scale softmax attention -----------
// One wave per point. A = h1 (32 rows: 30 neighbors + 2 pad, K=64 channels),
// B = W2^T, same k-permutation both sides. C/D: n = lane&15, m = (lane>>4)*4+reg.
__global__ __launch_bounds__(256) void pcc_mlp_mfma(
    const float4v* __restrict__ xq, const float* __restrict__ w1,
    const float* __restrict__ g1, const float* __restrict__ b1,
    const float* __restrict__ w2, const float* __restrict__ g2,
    const float* __restrict__ b2, const float* __restrict__ wa,
    const float* __restrict__ ba, const float* __restrict__ ga,
    const float* __restrict__ bga, const int* __restrict__ knn,
    float* __restrict__ out) {
  __shared__ float w1row[64][8];  // per channel: w1[0..5], s1, be1  (2 KB)
  const int tid = threadIdx.x;
  const float invs = 1.0f / sqrtf(1.0f + 1e-5f);
  for (int idx = tid; idx < 512; idx += 256) {
    const int c = idx >> 3, s = idx & 7;
    float v;
    if (s < 6) v = w1[c * 6 + s];
    else if (s == 6) v = g1[c] * invs;
    else v = b1[c];
    w1row[c][s] = v;
  }
  __syncthreads();

  const int wv = tid >> 6, lane = tid & 63;
  const int q = lane & 15, g = lane >> 4;
  const int row = (blockIdx.x << 2) + wv;
  const int b = row >> 12, n = row & (NPT - 1);
  const float4v* xqb = xq + ((size_t)b << 12);

  // B fragments: bf[kt][nt] elem e = B[k=kt*32+g*8+e][n=nt*16+q] = w2[n][k]
  short8v bf[2][4];
#pragma unroll
  for (int kt = 0; kt < 2; ++kt)
#pragma unroll
    for (int nt = 0; nt < 4; ++nt) {
      const float* src = w2 + (nt * 16 + q) * 64 + kt * 32 + g * 8;
      const float4v lo = *(const float4v*)(src);
      const float4v hi = *(const float4v*)(src + 4);
      short8v tt;
#pragma unroll
      for (int e = 0; e < 4; ++e) tt[e] = f2bf(lo[e]);
#pragma unroll
      for (int e = 0; e < 4; ++e) tt[4 + e] = f2bf(hi[e]);
      bf[kt][nt] = tt;
    }

  float s2r[4], be2r[4], war[4];
#pragma unroll
  for (int nt = 0; nt < 4; ++nt) {
    s2r[nt] = g2[q + 16 * nt] * invs;
    be2r[nt] = b2[q + 16 * nt];
    war[nt] = wa[q + 16 * nt];
  }
  const float sa = ga[0] * invs, ba0 = ba[0], bga0 = bga[0];

  const float4v qv = xqb[n];
  const float xn0 = qv[0], xn1 = qv[1], xn2 = qv[2];

  // neighbor coords for A rows m=q (j=q) and m=16+q (j=16+q, valid iff q<14)
  const int j0 = knn[row * 32 + q];
  const float4v c0 = xqb[j0];
  float a1x = xn0, a1y = xn1, a1z = xn2;  // pad row: d=0, finite
  if (q < 14) {
    const int j1 = knn[row * 32 + 16 + q];
    const float4v c1 = xqb[j1];
    a1x = c1[0]; a1y = c1[1]; a1z = c1[2];
  }
  const float d0x = c0[0] - xn0, d0y = c0[1] - xn1, d0z = c0[2] - xn2;
  const float d1x = a1x - xn0, d1y = a1y - xn1, d1z = a1z - xn2;

  float4v dfr[2][4];
#pragma unroll
  for (int mt = 0; mt < 2; ++mt)
#pragma unroll
    for (int nt = 0; nt < 4; ++nt) dfr[mt][nt] = (float4v){0.f, 0.f, 0.f, 0.f};

#pragma unroll
  for (int kt = 0; kt < 2; ++kt) {
    short8v af0, af1;
#pragma unroll
    for (int e = 0; e < 8; ++e) {
      const int c = kt * 32 + g * 8 + e;
      const float4v wlo = *(const float4v*)&w1row[c][0];
      const float4v whi = *(const float4v*)&w1row[c][4];
      float h = wlo[0] * d0x;
      h = fmaf(wlo[1], d0y, h);
      h = fmaf(wlo[2], d0z, h);
      h = fmaf(wlo[3], xn0, h);
      h = fmaf(whi[0], xn1, h);
      h = fmaf(whi[1], xn2, h);
      h = fmaf(h, whi[2], whi[3]);
      h = fmaxf(h, 0.2f * h);
      af0[e] = f2bf(h);
      float h1v = wlo[0] * d1x;
      h1v = fmaf(wlo[1], d1y, h1v);
      h1v = fmaf(wlo[2], d1z, h1v);
      h1v = fmaf(wlo[3], xn0, h1v);
      h1v = fmaf(whi[0], xn1, h1v);
      h1v = fmaf(whi[1], xn2, h1v);
      h1v = fmaf(h1v, whi[2], whi[3]);
      h1v = fmaxf(h1v, 0.2f * h1v);
      af1[e] = f2bf(h1v);
    }
#pragma unroll
    for (int nt = 0; nt < 4; ++nt) {
      dfr[0][nt] = __builtin_amdgcn_mfma_f32_16x16x32_bf16(af0, bf[kt][nt], dfr[0][nt], 0, 0, 0);
      dfr[1][nt] = __builtin_amdgcn_mfma_f32_16x16x32_bf16(af1, bf[kt][nt], dfr[1][nt], 0, 0, 0);
    }
  }

  float part[2][4];
#pragma unroll
  for (int mt = 0; mt < 2; ++mt)
#pragma unroll
    for (int r = 0; r < 4; ++r) part[mt][r] = 0.f;
#pragma unroll
  for (int mt = 0; mt < 2; ++mt)
#pragma unroll
    for (int nt = 0; nt < 4; ++nt) {
      float4v d = dfr[mt][nt];
#pragma unroll
      for (int r = 0; r < 4; ++r) {
        float h2 = fmaf(d[r], s2r[nt], be2r[nt]);
        h2 = fmaxf(h2, 0.2f * h2);
        d[r] = h2;
        part[mt][r] = fmaf(war[nt], h2, part[mt][r]);
      }
      dfr[mt][nt] = d;
    }
#pragma unroll
  for (int mt = 0; mt < 2; ++mt)
#pragma unroll
    for (int r = 0; r < 4; ++r) {
      float p = part[mt][r];
      p += __shfl_xor(p, 1, 64);
      p += __shfl_xor(p, 2, 64);
      p += __shfl_xor(p, 4, 64);
      p += __shfl_xor(p, 8, 64);
      part[mt][r] = p;
    }

  const int mrow = g * 4;
  float sc0[4], sc1[4];
  float mloc = -3.0e38f;
#pragma unroll
  for (int r = 0; r < 4; ++r) {
    float a = fmaf(part[0][r] + ba0, sa, bga0);
    a = fmaxf(a, 0.2f * a);
    sc0[r] = a;
    mloc = fmaxf(mloc, a);
  }
#pragma unroll
  for (int r = 0; r < 4; ++r) {
    float a = fmaf(part[1][r] + ba0, sa, bga0);
    a = fmaxf(a, 0.2f * a);
    sc1[r] = a;
    if (mrow + r < 14) mloc = fmaxf(mloc, a);
  }
  mloc = fmaxf(mloc, __shfl_xor(mloc, 16, 64));
  mloc = fmaxf(mloc, __shfl_xor(mloc, 32, 64));

  float e0[4], e1[4];
  float l10 = 0.f, l20 = 0.f, l30 = 0.f;
#pragma unroll
  for (int r = 0; r < 4; ++r) {
    const float vv = expf(sc0[r] - mloc);
    e0[r] = vv;
    l30 += vv;
    l20 += vv;
    if (mrow + r < 10) l10 += vv;
  }
#pragma unroll
  for (int r = 0; r < 4; ++r) {
    const float vv = (mrow + r < 14) ? expf(sc1[r] - mloc) : 0.f;
    e1[r] = vv;
    l30 += vv;
    if (mrow + r < 4) l20 += vv;
  }
  l10 += __shfl_xor(l10, 16, 64); l10 += __shfl_xor(l10, 32, 64);
  l20 += __shfl_xor(l20, 16, 64); l20 += __shfl_xor(l20, 32, 64);
  l30 += __shfl_xor(l30, 16, 64); l30 += __shfl_xor(l30, 32, 64);
  const float i10 = 1.0f / l10, i20 = 1.0f / l20, i30 = 1.0f / l30;
  const float third = 1.0f / 3.0f;

  float wgt0[4], wgt1[4];
#pragma unroll
  for (int r = 0; r < 4; ++r) {
    wgt0[r] = e0[r] * (((mrow + r < 10) ? i10 : 0.f) + i20 + i30) * third;
    wgt1[r] = e1[r] * (((mrow + r < 4) ? i20 : 0.f) + i30) * third;
  }

  float acc[4] = {0.f, 0.f, 0.f, 0.f};
#pragma unroll
  for (int nt = 0; nt < 4; ++nt) {
#pragma unroll
    for (int r = 0; r < 4; ++r) {
      acc[nt] = fmaf(wgt0[r], dfr[0][nt][r], acc[nt]);
      acc[nt] = fmaf(wgt1[r], dfr[1][nt][r], acc[nt]);
    }
  }
#pragma unroll
  for (int nt = 0; nt < 4; ++nt) {
    acc[nt] += __shfl_xor(acc[nt], 16, 64);
    acc[nt] += __shfl_xor(acc[nt], 32, 64);
  }
  const float val = (g == 0) ? acc[0] : (g == 1) ? acc[1] : (g == 2) ? acc[2] : acc[3];
  out[(size_t)(b * 64 + q + 16 * g) * NPT + n] = val;
}

extern "C" void kernel_launch(void* const* d_in, const int* in_sizes, int n_in,
                              void* d_out, int out_size, void* d_ws, size_t ws_size,
                              hipStream_t stream) {
  const float* x = (const float*)d_in[0];
  const float* w1 = (const float*)d_in[1];
  const float* g1 = (const float*)d_in[2];
  const float* b1 = (const float*)d_in[3];
  const float* w2 = (const float*)d_in[4];
  const float* g2 = (const float*)d_in[5];
  const float* b2 = (const float*)d_in[6];
  const float* wa = (const float*)d_in[7];
  const float* ba = (const float*)d_in[8];
  const float* ga = (const float*)d_in[9];
  const float* bga = (const float*)d_in[10];
  float* out = (float*)d_out;

  float4v* xq = (float4v*)d_ws;                       // 32768 * 16 B = 512 KB
  int* knn = (int*)((char*)d_ws + ROWS * 16);         // [ROWS][32] ints = 4 MB

  prep_kernel<<<dim3(ROWS / 256), dim3(256), 0, stream>>>(x, xq);
  knn_kernel<<<dim3(ROWS / 4), dim3(256), 0, stream>>>(xq, knn);
  pcc_mlp_mfma<<<dim3(ROWS / 4), dim3(256), 0, stream>>>(
      xq, w1, g1, b1, w2, g2, b2, wa, ba, ga, bga, knn, out);
}

// Round 4
// 149.876 us; speedup vs baseline: 2.8041x; 1.4492x over previous
//
#include <hip/hip_runtime.h>
#include <math.h>

// PCCNet: KNN(30) + per-neighbor MLP(6->64->64) + 3-scale prefix softmax attention.
// Round 4: knn tiled 8 queries/wave, two-pass (threshold then ballot-compact) to
// cut L1 candidate traffic 4x. W2 bf16 fragments pre-packed in prep kernel.

#define NB 8
#define NPT 4096
#define KMAXK 30
#define ROWS (NB * NPT)
#define QW 8     // queries per wave
#define SCAP 96  // survivor cap per query (observed ~48)

typedef __attribute__((ext_vector_type(8))) short short8v;
typedef __attribute__((ext_vector_type(4))) float float4v;

__device__ __forceinline__ unsigned long long shflx64(unsigned long long v, int m) {
  unsigned lo = (unsigned)__shfl_xor((int)(unsigned)(v & 0xFFFFFFFFull), m, 64);
  unsigned hi = (unsigned)__shfl_xor((int)(unsigned)(v >> 32), m, 64);
  return ((unsigned long long)hi << 32) | (unsigned long long)lo;
}

__device__ __forceinline__ short f2bf(float x) {  // f32 -> bf16 RNE
  unsigned u = __float_as_uint(x);
  return (short)((u + 0x7FFFu + ((u >> 16) & 1u)) >> 16);
}

__device__ __forceinline__ unsigned ordkey(float f) {  // monotonic u32 of f32
  const unsigned bits = __float_as_uint(f);
  return bits ^ ((unsigned)((int)bits >> 31) | 0x80000000u);
}

__device__ __forceinline__ float sbcast(float v) {  // force wave-uniform -> SGPR
  return __int_as_float(__builtin_amdgcn_readfirstlane(__float_as_int(v)));
}

// ---------------- Kernel 0: pack (x,y,z,|x|^2) + pack W2 bf16 fragments ----
__global__ __launch_bounds__(256) void prep_kernel(const float* __restrict__ x,
                                                   const float* __restrict__ w2,
                                                   float4v* __restrict__ xq,
                                                   short8v* __restrict__ w2bf) {
  const int i = blockIdx.x * 256 + threadIdx.x;
  if (i < ROWS) {
    const int b = i >> 12, m = i & (NPT - 1);
    const float* xb = x + (size_t)b * 3 * NPT;
    const float y0 = xb[m], y1 = xb[NPT + m], y2 = xb[2 * NPT + m];
    const float xx = y0 * y0 + y1 * y1 + y2 * y2;
    xq[i] = (float4v){y0, y1, y2, xx};
  }
  if (blockIdx.x == ROWS / 256) {
    // 512 fragment vectors: v = (kt*4+nt)*64 + lane; elem e = w2[nt*16+q][kt*32+g*8+e]
#pragma unroll
    for (int u = 0; u < 2; ++u) {
      const int v = threadIdx.x * 2 + u;
      const int lane = v & 63, fi = v >> 6;
      const int kt = fi >> 2, nt = fi & 3;
      const int q = lane & 15, g = lane >> 4;
      const float* src = w2 + (nt * 16 + q) * 64 + kt * 32 + g * 8;
      short8v tt;
#pragma unroll
      for (int e = 0; e < 8; ++e) tt[e] = f2bf(src[e]);
      w2bf[v] = tt;
    }
  }
}

// ---------------- Kernel 1: exact top-30 neighbor indices, 8 queries/wave --
__global__ __launch_bounds__(256, 6) void knn_kernel(const float4v* __restrict__ xq,
                                                     int* __restrict__ knn) {
  __shared__ unsigned long long buf[4][QW][SCAP];  // 24 KB
  const int wv = threadIdx.x >> 6;
  const int lane = threadIdx.x & 63;
  const int row0 = ((blockIdx.x << 2) + wv) * QW;  // 8 consecutive points, same batch
  const int b = row0 >> 12;
  const int n0 = row0 & (NPT - 1);
  const float4v* xqb = xq + ((size_t)b << 12);

  // wave-uniform query constants in SGPRs
  float qx[QW], qy[QW], qz[QW], qq[QW];
#pragma unroll
  for (int qi = 0; qi < QW; ++qi) {
    const float4v qv = xqb[n0 + qi];
    qx[qi] = sbcast(qv[0]);
    qy[qi] = sbcast(qv[1]);
    qz[qi] = sbcast(qv[2]);
    qq[qi] = sbcast(qv[3]);
  }

  // ---- pass 1: per-query lane-max over this lane's 64 candidates ----
  float kmax[QW];
#pragma unroll
  for (int qi = 0; qi < QW; ++qi) kmax[qi] = -3.0e38f;
  for (int j = 0; j < 64; ++j) {
    const int m = (j << 6) + lane;
    const float4v c = xqb[m];
#pragma unroll
    for (int qi = 0; qi < QW; ++qi) {
      float inner = c[0] * qx[qi];
      inner = fmaf(c[1], qy[qi], inner);
      inner = fmaf(c[2], qz[qi], inner);
      const float pd = 2.0f * inner - qq[qi] - c[3];
      kmax[qi] = fmaxf(kmax[qi], pd);
    }
  }

  // per-query threshold: 30th largest of the 64 lane-maxima (exact-safe)
  float thr[QW];
#pragma unroll
  for (int qi = 0; qi < QW; ++qi) {
    float v = kmax[qi];
#pragma unroll
    for (int kk = 2; kk <= 64; kk <<= 1) {
#pragma unroll
      for (int jj = 32; jj >= 1; jj >>= 1) {
        if (jj < kk) {
          const float o = __shfl_xor(v, jj, 64);
          const bool up = ((lane & kk) == 0);
          const bool takeMax = (((lane & jj) != 0) == up);
          v = takeMax ? fmaxf(v, o) : fminf(v, o);
        }
      }
    }
    thr[qi] = sbcast(__shfl(v, 34, 64));  // 35th smallest == 30th largest
  }

  // ---- pass 2: recompute + ballot-compact survivors per query ----
  int cnt[QW];
#pragma unroll
  for (int qi = 0; qi < QW; ++qi) cnt[qi] = 0;
  for (int j = 0; j < 64; ++j) {
    const int m = (j << 6) + lane;
    const float4v c = xqb[m];
#pragma unroll
    for (int qi = 0; qi < QW; ++qi) {
      float inner = c[0] * qx[qi];
      inner = fmaf(c[1], qy[qi], inner);
      inner = fmaf(c[2], qz[qi], inner);
      const float pd = 2.0f * inner - qq[qi] - c[3];
      const bool pred = pd >= thr[qi];
      const unsigned long long mask = __ballot(pred);
      if (pred) {
        const int pos = cnt[qi] + (int)__popcll(mask & ((1ull << lane) - 1ull));
        if (pos < SCAP) {
          buf[wv][qi][pos] = ((unsigned long long)ordkey(pd) << 32) | (unsigned)(4095 - m);
        }
      }
      cnt[qi] += (int)__popcll(mask);
    }
  }

  // ---- selection per query ----
#pragma unroll 1
  for (int qi = 0; qi < QW; ++qi) {
    const int c = cnt[qi];
    const int outbase = (row0 + qi) * 32;
    if (c >= KMAXK && c <= 64) {
      // typical: 64-lane bitonic sort ascending of packed (key, 4095-m)
      unsigned long long val = (lane < c) ? buf[wv][qi][lane] : 0ull;
#pragma unroll
      for (int kk = 2; kk <= 64; kk <<= 1) {
#pragma unroll
        for (int jj = 32; jj >= 1; jj >>= 1) {
          if (jj < kk) {
            const unsigned long long o = shflx64(val, jj);
            const bool up = ((lane & kk) == 0);
            const bool takeMax = (((lane & jj) != 0) == up);
            const unsigned long long mx = val > o ? val : o;
            const unsigned long long mn = val > o ? o : val;
            val = takeMax ? mx : mn;
          }
        }
      }
      const int rank = 63 - lane;
      if (rank < KMAXK) {
        const int m = 4095 - (int)(val & 0xFFFFFFFFull);
        knn[outbase + rank] = m;
      }
    } else if (c > 64 && c <= SCAP) {
      // uncommon: iterative wave-argmax over LDS survivors
      for (int r = 0; r < KMAXK; ++r) {
        unsigned long long lmax = 0ull;
        int lpos = -1;
        for (int p = lane; p < c; p += 64) {
          const unsigned long long q2 = buf[wv][qi][p];
          if (q2 > lmax) { lmax = q2; lpos = p; }
        }
        unsigned long long g = lmax;
#pragma unroll
        for (int s = 32; s >= 1; s >>= 1) {
          const unsigned long long o = shflx64(g, s);
          g = o > g ? o : g;
        }
        const unsigned long long pm = __ballot(lmax == g && lpos >= 0);
        const int lowlane = (int)(__ffsll((unsigned long long)pm) - 1);
        if (lane == lowlane) buf[wv][qi][lpos] = 0ull;
        if (lane == 0) knn[outbase + r] = 4095 - (int)(g & 0xFFFFFFFFull);
      }
    } else {
      // pathological (never expected): exact scan-select from global, 30 rounds
      unsigned long long prev = ~0ull;
      for (int r = 0; r < KMAXK; ++r) {
        unsigned long long best = 0ull;
        for (int j = 0; j < 64; ++j) {
          const int m = (j << 6) + lane;
          const float4v cc = xqb[m];
          float inner = cc[0] * qx[qi];
          inner = fmaf(cc[1], qy[qi], inner);
          inner = fmaf(cc[2], qz[qi], inner);
          const float pd = 2.0f * inner - qq[qi] - cc[3];
          const unsigned long long key =
              ((unsigned long long)ordkey(pd) << 32) | (unsigned)(4095 - m);
          if (key < prev && key > best) best = key;
        }
#pragma unroll
        for (int s = 32; s >= 1; s >>= 1) {
          const unsigned long long o = shflx64(best, s);
          best = o > best ? o : best;
        }
        if (lane == 0) knn[outbase + r] = 4095 - (int)(best & 0xFFFFFFFFull);
        prev = best;
      }
    }
  }
}

// ---------------- Kernel 2: MFMA MLP + 3-scale softmax attention -----------
// One wave per point. A = h1 (32 rows: 30 neighbors + 2 pad, K=64 channels),
// B = W2^T (pre-packed bf16 frags). C/D: n = lane&15, m = (lane>>4)*4+reg.
__global__ __launch_bounds__(256) void pcc_mlp_mfma(
    const float4v* __restrict__ xq, const float* __restrict__ w1,
    const float* __restrict__ g1, const float* __restrict__ b1,
    const short8v* __restrict__ w2bf, const float* __restrict__ g2,
    const float* __restrict__ b2, const float* __restrict__ wa,
    const float* __restrict__ ba, const float* __restrict__ ga,
    const float* __restrict__ bga, const int* __restrict__ knn,
    float* __restrict__ out) {
  __shared__ float w1row[64][8];  // per channel: w1[0..5], s1, be1  (2 KB)
  const int tid = threadIdx.x;
  const float invs = 1.0f / sqrtf(1.0f + 1e-5f);
  for (int idx = tid; idx < 512; idx += 256) {
    const int c = idx >> 3, s = idx & 7;
    float v;
    if (s < 6) v = w1[c * 6 + s];
    else if (s == 6) v = g1[c] * invs;
    else v = b1[c];
    w1row[c][s] = v;
  }
  __syncthreads();

  const int wv = tid >> 6, lane = tid & 63;
  const int q = lane & 15, g = lane >> 4;
  const int row = (blockIdx.x << 2) + wv;
  const int b = row >> 12, n = row & (NPT - 1);
  const float4v* xqb = xq + ((size_t)b << 12);

  short8v bf[2][4];
#pragma unroll
  for (int kt = 0; kt < 2; ++kt)
#pragma unroll
    for (int nt = 0; nt < 4; ++nt) bf[kt][nt] = w2bf[((kt << 2) + nt) * 64 + lane];

  float s2r[4], be2r[4], war[4];
#pragma unroll
  for (int nt = 0; nt < 4; ++nt) {
    s2r[nt] = g2[q + 16 * nt] * invs;
    be2r[nt] = b2[q + 16 * nt];
    war[nt] = wa[q + 16 * nt];
  }
  const float sa = ga[0] * invs, ba0 = ba[0], bga0 = bga[0];

  const float4v qv = xqb[n];
  const float xn0 = qv[0], xn1 = qv[1], xn2 = qv[2];

  const int j0 = knn[row * 32 + q];
  const float4v c0 = xqb[j0];
  float a1x = xn0, a1y = xn1, a1z = xn2;  // pad row: d=0, finite
  if (q < 14) {
    const int j1 = knn[row * 32 + 16 + q];
    const float4v c1 = xqb[j1];
    a1x = c1[0]; a1y = c1[1]; a1z = c1[2];
  }
  const float d0x = c0[0] - xn0, d0y = c0[1] - xn1, d0z = c0[2] - xn2;
  const float d1x = a1x - xn0, d1y = a1y - xn1, d1z = a1z - xn2;

  float4v dfr[2][4];
#pragma unroll
  for (int mt = 0; mt < 2; ++mt)
#pragma unroll
    for (int nt = 0; nt < 4; ++nt) dfr[mt][nt] = (float4v){0.f, 0.f, 0.f, 0.f};

#pragma unroll
  for (int kt = 0; kt < 2; ++kt) {
    short8v af0, af1;
#pragma unroll
    for (int e = 0; e < 8; ++e) {
      const int c = kt * 32 + g * 8 + e;
      const float4v wlo = *(const float4v*)&w1row[c][0];
      const float4v whi = *(const float4v*)&w1row[c][4];
      float h = wlo[0] * d0x;
      h = fmaf(wlo[1], d0y, h);
      h = fmaf(wlo[2], d0z, h);
      h = fmaf(wlo[3], xn0, h);
      h = fmaf(whi[0], xn1, h);
      h = fmaf(whi[1], xn2, h);
      h = fmaf(h, whi[2], whi[3]);
      h = fmaxf(h, 0.2f * h);
      af0[e] = f2bf(h);
      float h1v = wlo[0] * d1x;
      h1v = fmaf(wlo[1], d1y, h1v);
      h1v = fmaf(wlo[2], d1z, h1v);
      h1v = fmaf(wlo[3], xn0, h1v);
      h1v = fmaf(whi[0], xn1, h1v);
      h1v = fmaf(whi[1], xn2, h1v);
      h1v = fmaf(h1v, whi[2], whi[3]);
      h1v = fmaxf(h1v, 0.2f * h1v);
      af1[e] = f2bf(h1v);
    }
#pragma unroll
    for (int nt = 0; nt < 4; ++nt) {
      dfr[0][nt] = __builtin_amdgcn_mfma_f32_16x16x32_bf16(af0, bf[kt][nt], dfr[0][nt], 0, 0, 0);
      dfr[1][nt] = __builtin_amdgcn_mfma_f32_16x16x32_bf16(af1, bf[kt][nt], dfr[1][nt], 0, 0, 0);
    }
  }

  float part[2][4];
#pragma unroll
  for (int mt = 0; mt < 2; ++mt)
#pragma unroll
    for (int r = 0; r < 4; ++r) part[mt][r] = 0.f;
#pragma unroll
  for (int mt = 0; mt < 2; ++mt)
#pragma unroll
    for (int nt = 0; nt < 4; ++nt) {
      float4v d = dfr[mt][nt];
#pragma unroll
      for (int r = 0; r < 4; ++r) {
        float h2 = fmaf(d[r], s2r[nt], be2r[nt]);
        h2 = fmaxf(h2, 0.2f * h2);
        d[r] = h2;
        part[mt][r] = fmaf(war[nt], h2, part[mt][r]);
      }
      dfr[mt][nt] = d;
    }
#pragma unroll
  for (int mt = 0; mt < 2; ++mt)
#pragma unroll
    for (int r = 0; r < 4; ++r) {
      float p = part[mt][r];
      p += __shfl_xor(p, 1, 64);
      p += __shfl_xor(p, 2, 64);
      p += __shfl_xor(p, 4, 64);
      p += __shfl_xor(p, 8, 64);
      part[mt][r] = p;
    }

  const int mrow = g * 4;
  float sc0[4], sc1[4];
  float mloc = -3.0e38f;
#pragma unroll
  for (int r = 0; r < 4; ++r) {
    float a = fmaf(part[0][r] + ba0, sa, bga0);
    a = fmaxf(a, 0.2f * a);
    sc0[r] = a;
    mloc = fmaxf(mloc, a);
  }
#pragma unroll
  for (int r = 0; r < 4; ++r) {
    float a = fmaf(part[1][r] + ba0, sa, bga0);
    a = fmaxf(a, 0.2f * a);
    sc1[r] = a;
    if (mrow + r < 14) mloc = fmaxf(mloc, a);
  }
  mloc = fmaxf(mloc, __shfl_xor(mloc, 16, 64));
  mloc = fmaxf(mloc, __shfl_xor(mloc, 32, 64));

  float e0[4], e1[4];
  float l10 = 0.f, l20 = 0.f, l30 = 0.f;
#pragma unroll
  for (int r = 0; r < 4; ++r) {
    const float vv = expf(sc0[r] - mloc);
    e0[r] = vv;
    l30 += vv;
    l20 += vv;
    if (mrow + r < 10) l10 += vv;
  }
#pragma unroll
  for (int r = 0; r < 4; ++r) {
    const float vv = (mrow + r < 14) ? expf(sc1[r] - mloc) : 0.f;
    e1[r] = vv;
    l30 += vv;
    if (mrow + r < 4) l20 += vv;
  }
  l10 += __shfl_xor(l10, 16, 64); l10 += __shfl_xor(l10, 32, 64);
  l20 += __shfl_xor(l20, 16, 64); l20 += __shfl_xor(l20, 32, 64);
  l30 += __shfl_xor(l30, 16, 64); l30 += __shfl_xor(l30, 32, 64);
  const float i10 = 1.0f / l10, i20 = 1.0f / l20, i30 = 1.0f / l30;
  const float third = 1.0f / 3.0f;

  float wgt0[4], wgt1[4];
#pragma unroll
  for (int r = 0; r < 4; ++r) {
    wgt0[r] = e0[r] * (((mrow + r < 10) ? i10 : 0.f) + i20 + i30) * third;
    wgt1[r] = e1[r] * (((mrow + r < 4) ? i20 : 0.f) + i30) * third;
  }

  float acc[4] = {0.f, 0.f, 0.f, 0.f};
#pragma unroll
  for (int nt = 0; nt < 4; ++nt) {
#pragma unroll
    for (int r = 0; r < 4; ++r) {
      acc[nt] = fmaf(wgt0[r], dfr[0][nt][r], acc[nt]);
      acc[nt] = fmaf(wgt1[r], dfr[1][nt][r], acc[nt]);
    }
  }
#pragma unroll
  for (int nt = 0; nt < 4; ++nt) {
    acc[nt] += __shfl_xor(acc[nt], 16, 64);
    acc[nt] += __shfl_xor(acc[nt], 32, 64);
  }
  const float val = (g == 0) ? acc[0] : (g == 1) ? acc[1] : (g == 2) ? acc[2] : acc[3];
  out[(size_t)(b * 64 + q + 16 * g) * NPT + n] = val;
}

extern "C" void kernel_launch(void* const* d_in, const int* in_sizes, int n_in,
                              void* d_out, int out_size, void* d_ws, size_t ws_size,
                              hipStream_t stream) {
  const float* x = (const float*)d_in[0];
  const float* w1 = (const float*)d_in[1];
  const float* g1 = (const float*)d_in[2];
  const float* b1 = (const float*)d_in[3];
  const float* w2 = (const float*)d_in[4];
  const float* g2 = (const float*)d_in[5];
  const float* b2 = (const float*)d_in[6];
  const float* wa = (const float*)d_in[7];
  const float* ba = (const float*)d_in[8];
  const float* ga = (const float*)d_in[9];
  const float* bga = (const float*)d_in[10];
  float* out = (float*)d_out;

  float4v* xq = (float4v*)d_ws;                         // 512 KB
  int* knn = (int*)((char*)d_ws + ROWS * 16);           // 4 MB
  short8v* w2bf = (short8v*)((char*)d_ws + ROWS * 16 + ROWS * 32 * 4);  // 8 KB

  prep_kernel<<<dim3(ROWS / 256 + 1), dim3(256), 0, stream>>>(x, w2, xq, w2bf);
  knn_kernel<<<dim3(ROWS / (4 * QW)), dim3(256), 0, stream>>>(xq, knn);
  pcc_mlp_mfma<<<dim3(ROWS / 4), dim3(256), 0, stream>>>(
      xq, w1, g1, b1, w2bf, g2, b2, wa, ba, ga, bga, knn, out);
}

// Round 5
// 146.845 us; speedup vs baseline: 2.8620x; 1.0206x over previous
//
#include <hip/hip_runtime.h>
#include <math.h>

// PCCNet: KNN(30) + per-neighbor MLP(6->64->64) + 3-scale prefix softmax attention.
// Round 5: knn QW=4 (grid 2048 -> ~24 waves/CU) + packed v_pk_fma_f32 distance
// math in both passes (bit-identical rounding to the scalar chain). MLP unchanged.

#define NB 8
#define NPT 4096
#define KMAXK 30
#define ROWS (NB * NPT)
#define QW 4     // queries per wave
#define SCAP 96  // survivor cap per query (observed ~48)

typedef __attribute__((ext_vector_type(8))) short short8v;
typedef __attribute__((ext_vector_type(4))) float float4v;
typedef __attribute__((ext_vector_type(2))) float float2v;

__device__ __forceinline__ unsigned long long shflx64(unsigned long long v, int m) {
  unsigned lo = (unsigned)__shfl_xor((int)(unsigned)(v & 0xFFFFFFFFull), m, 64);
  unsigned hi = (unsigned)__shfl_xor((int)(unsigned)(v >> 32), m, 64);
  return ((unsigned long long)hi << 32) | (unsigned long long)lo;
}

__device__ __forceinline__ short f2bf(float x) {  // f32 -> bf16 RNE
  unsigned u = __float_as_uint(x);
  return (short)((u + 0x7FFFu + ((u >> 16) & 1u)) >> 16);
}

__device__ __forceinline__ unsigned ordkey(float f) {  // monotonic u32 of f32
  const unsigned bits = __float_as_uint(f);
  return bits ^ ((unsigned)((int)bits >> 31) | 0x80000000u);
}

__device__ __forceinline__ float sbcast(float v) {  // force wave-uniform -> SGPR
  return __int_as_float(__builtin_amdgcn_readfirstlane(__float_as_int(v)));
}

// ---------------- Kernel 0: pack (x,y,z,|x|^2) + pack W2 bf16 fragments ----
__global__ __launch_bounds__(256) void prep_kernel(const float* __restrict__ x,
                                                   const float* __restrict__ w2,
                                                   float4v* __restrict__ xq,
                                                   short8v* __restrict__ w2bf) {
  const int i = blockIdx.x * 256 + threadIdx.x;
  if (i < ROWS) {
    const int b = i >> 12, m = i & (NPT - 1);
    const float* xb = x + (size_t)b * 3 * NPT;
    const float y0 = xb[m], y1 = xb[NPT + m], y2 = xb[2 * NPT + m];
    const float xx = y0 * y0 + y1 * y1 + y2 * y2;
    xq[i] = (float4v){y0, y1, y2, xx};
  }
  if (blockIdx.x == ROWS / 256) {
    // 512 fragment vectors: v = (kt*4+nt)*64 + lane; elem e = w2[nt*16+q][kt*32+g*8+e]
#pragma unroll
    for (int u = 0; u < 2; ++u) {
      const int v = threadIdx.x * 2 + u;
      const int lane = v & 63, fi = v >> 6;
      const int kt = fi >> 2, nt = fi & 3;
      const int q = lane & 15, g = lane >> 4;
      const float* src = w2 + (nt * 16 + q) * 64 + kt * 32 + g * 8;
      short8v tt;
#pragma unroll
      for (int e = 0; e < 8; ++e) tt[e] = f2bf(src[e]);
      w2bf[v] = tt;
    }
  }
}

// ---------------- Kernel 1: exact top-30 neighbor indices, 4 queries/wave --
// Packed-f32 distances: per element identical rounding to the scalar chain
// (mul,fma,fma; then 2*inner exact, -qq, -c3) -> keys bit-identical.
__global__ __launch_bounds__(256, 6) void knn_kernel(const float4v* __restrict__ xq,
                                                     int* __restrict__ knn) {
  __shared__ unsigned long long buf[4][QW][SCAP];  // 12 KB
  const int wv = threadIdx.x >> 6;
  const int lane = threadIdx.x & 63;
  const int row0 = ((blockIdx.x << 2) + wv) * QW;  // 4 consecutive points, same batch
  const int b = row0 >> 12;
  const int n0 = row0 & (NPT - 1);
  const float4v* xqb = xq + ((size_t)b << 12);

  // wave-uniform query constants
  float qx[QW], qy[QW], qz[QW], qq[QW];
#pragma unroll
  for (int qi = 0; qi < QW; ++qi) {
    const float4v qv = xqb[n0 + qi];
    qx[qi] = sbcast(qv[0]);
    qy[qi] = sbcast(qv[1]);
    qz[qi] = sbcast(qv[2]);
    qq[qi] = sbcast(qv[3]);
  }
  float2v qxp[2], qyp[2], qzp[2], qqp[2];
#pragma unroll
  for (int p = 0; p < 2; ++p) {
    qxp[p] = (float2v){qx[2 * p], qx[2 * p + 1]};
    qyp[p] = (float2v){qy[2 * p], qy[2 * p + 1]};
    qzp[p] = (float2v){qz[2 * p], qz[2 * p + 1]};
    qqp[p] = (float2v){qq[2 * p], qq[2 * p + 1]};
  }

  // ---- pass 1: per-query lane-max over this lane's 64 candidates ----
  float2v kmaxp[2];
  kmaxp[0] = (float2v){-3.0e38f, -3.0e38f};
  kmaxp[1] = (float2v){-3.0e38f, -3.0e38f};
  for (int j = 0; j < 64; ++j) {
    const float4v c = xqb[(j << 6) + lane];
    const float2v cx = (float2v){c[0], c[0]};
    const float2v cy = (float2v){c[1], c[1]};
    const float2v cz = (float2v){c[2], c[2]};
    const float2v cw = (float2v){c[3], c[3]};
#pragma unroll
    for (int p = 0; p < 2; ++p) {
      float2v inner = cx * qxp[p];
      inner = __builtin_elementwise_fma(cy, qyp[p], inner);
      inner = __builtin_elementwise_fma(cz, qzp[p], inner);
      const float2v pd = (inner + inner) - qqp[p] - cw;
      kmaxp[p] = __builtin_elementwise_max(kmaxp[p], pd);
    }
  }
  const float kmaxs[QW] = {kmaxp[0][0], kmaxp[0][1], kmaxp[1][0], kmaxp[1][1]};

  // per-query threshold: 30th largest of the 64 lane-maxima, minus eps slack
  float thr[QW];
#pragma unroll
  for (int qi = 0; qi < QW; ++qi) {
    float v = kmaxs[qi];
#pragma unroll
    for (int kk = 2; kk <= 64; kk <<= 1) {
#pragma unroll
      for (int jj = 32; jj >= 1; jj >>= 1) {
        if (jj < kk) {
          const float o = __shfl_xor(v, jj, 64);
          const bool up = ((lane & kk) == 0);
          const bool takeMax = (((lane & jj) != 0) == up);
          v = takeMax ? fmaxf(v, o) : fminf(v, o);
        }
      }
    }
    thr[qi] = sbcast(__shfl(v, 34, 64)) - 1.0e-4f;  // eps: survivor superset only
  }

  // ---- pass 2: recompute (packed, bit-identical) + ballot-compact ----
  int cnt[QW];
#pragma unroll
  for (int qi = 0; qi < QW; ++qi) cnt[qi] = 0;
  for (int j = 0; j < 64; ++j) {
    const int m = (j << 6) + lane;
    const float4v c = xqb[m];
    const float2v cx = (float2v){c[0], c[0]};
    const float2v cy = (float2v){c[1], c[1]};
    const float2v cz = (float2v){c[2], c[2]};
    const float2v cw = (float2v){c[3], c[3]};
    float2v pdp[2];
#pragma unroll
    for (int p = 0; p < 2; ++p) {
      float2v inner = cx * qxp[p];
      inner = __builtin_elementwise_fma(cy, qyp[p], inner);
      inner = __builtin_elementwise_fma(cz, qzp[p], inner);
      pdp[p] = (inner + inner) - qqp[p] - cw;
    }
#pragma unroll
    for (int qi = 0; qi < QW; ++qi) {
      const float pd = pdp[qi >> 1][qi & 1];
      const bool pred = pd >= thr[qi];
      const unsigned long long mask = __ballot(pred);
      if (pred) {
        const int pos = cnt[qi] + (int)__popcll(mask & ((1ull << lane) - 1ull));
        if (pos < SCAP) {
          buf[wv][qi][pos] = ((unsigned long long)ordkey(pd) << 32) | (unsigned)(4095 - m);
        }
      }
      cnt[qi] += (int)__popcll(mask);
    }
  }

  // ---- selection per query ----
#pragma unroll 1
  for (int qi = 0; qi < QW; ++qi) {
    const int c = cnt[qi];
    const int outbase = (row0 + qi) * 32;
    if (c >= KMAXK && c <= 64) {
      // typical: 64-lane bitonic sort ascending of packed (key, 4095-m)
      unsigned long long val = (lane < c) ? buf[wv][qi][lane] : 0ull;
#pragma unroll
      for (int kk = 2; kk <= 64; kk <<= 1) {
#pragma unroll
        for (int jj = 32; jj >= 1; jj >>= 1) {
          if (jj < kk) {
            const unsigned long long o = shflx64(val, jj);
            const bool up = ((lane & kk) == 0);
            const bool takeMax = (((lane & jj) != 0) == up);
            const unsigned long long mx = val > o ? val : o;
            const unsigned long long mn = val > o ? o : val;
            val = takeMax ? mx : mn;
          }
        }
      }
      const int rank = 63 - lane;
      if (rank < KMAXK) {
        const int m = 4095 - (int)(val & 0xFFFFFFFFull);
        knn[outbase + rank] = m;
      }
    } else if (c > 64 && c <= SCAP) {
      // uncommon: iterative wave-argmax over LDS survivors
      for (int r = 0; r < KMAXK; ++r) {
        unsigned long long lmax = 0ull;
        int lpos = -1;
        for (int p = lane; p < c; p += 64) {
          const unsigned long long q2 = buf[wv][qi][p];
          if (q2 > lmax) { lmax = q2; lpos = p; }
        }
        unsigned long long g = lmax;
#pragma unroll
        for (int s = 32; s >= 1; s >>= 1) {
          const unsigned long long o = shflx64(g, s);
          g = o > g ? o : g;
        }
        const unsigned long long pm = __ballot(lmax == g && lpos >= 0);
        const int lowlane = (int)(__ffsll((unsigned long long)pm) - 1);
        if (lane == lowlane) buf[wv][qi][lpos] = 0ull;
        if (lane == 0) knn[outbase + r] = 4095 - (int)(g & 0xFFFFFFFFull);
      }
    } else {
      // pathological (never expected): exact scan-select from global, 30 rounds
      unsigned long long prev = ~0ull;
      for (int r = 0; r < KMAXK; ++r) {
        unsigned long long best = 0ull;
        for (int j = 0; j < 64; ++j) {
          const int m = (j << 6) + lane;
          const float4v cc = xqb[m];
          float inner = cc[0] * qx[qi];
          inner = fmaf(cc[1], qy[qi], inner);
          inner = fmaf(cc[2], qz[qi], inner);
          const float pd = 2.0f * inner - qq[qi] - cc[3];
          const unsigned long long key =
              ((unsigned long long)ordkey(pd) << 32) | (unsigned)(4095 - m);
          if (key < prev && key > best) best = key;
        }
#pragma unroll
        for (int s = 32; s >= 1; s >>= 1) {
          const unsigned long long o = shflx64(best, s);
          best = o > best ? o : best;
        }
        if (lane == 0) knn[outbase + r] = 4095 - (int)(best & 0xFFFFFFFFull);
        prev = best;
      }
    }
  }
}

// ---------------- Kernel 2: MFMA MLP + 3-scale softmax attention -----------
// One wave per point. A = h1 (32 rows: 30 neighbors + 2 pad, K=64 channels),
// B = W2^T (pre-packed bf16 frags). C/D: n = lane&15, m = (lane>>4)*4+reg.
__global__ __launch_bounds__(256) void pcc_mlp_mfma(
    const float4v* __restrict__ xq, const float* __restrict__ w1,
    const float* __restrict__ g1, const float* __restrict__ b1,
    const short8v* __restrict__ w2bf, const float* __restrict__ g2,
    const float* __restrict__ b2, const float* __restrict__ wa,
    const float* __restrict__ ba, const float* __restrict__ ga,
    const float* __restrict__ bga, const int* __restrict__ knn,
    float* __restrict__ out) {
  __shared__ float w1row[64][8];  // per channel: w1[0..5], s1, be1  (2 KB)
  const int tid = threadIdx.x;
  const float invs = 1.0f / sqrtf(1.0f + 1e-5f);
  for (int idx = tid; idx < 512; idx += 256) {
    const int c = idx >> 3, s = idx & 7;
    float v;
    if (s < 6) v = w1[c * 6 + s];
    else if (s == 6) v = g1[c] * invs;
    else v = b1[c];
    w1row[c][s] = v;
  }
  __syncthreads();

  const int wv = tid >> 6, lane = tid & 63;
  const int q = lane & 15, g = lane >> 4;
  const int row = (blockIdx.x << 2) + wv;
  const int b = row >> 12, n = row & (NPT - 1);
  const float4v* xqb = xq + ((size_t)b << 12);

  short8v bf[2][4];
#pragma unroll
  for (int kt = 0; kt < 2; ++kt)
#pragma unroll
    for (int nt = 0; nt < 4; ++nt) bf[kt][nt] = w2bf[((kt << 2) + nt) * 64 + lane];

  float s2r[4], be2r[4], war[4];
#pragma unroll
  for (int nt = 0; nt < 4; ++nt) {
    s2r[nt] = g2[q + 16 * nt] * invs;
    be2r[nt] = b2[q + 16 * nt];
    war[nt] = wa[q + 16 * nt];
  }
  const float sa = ga[0] * invs, ba0 = ba[0], bga0 = bga[0];

  const float4v qv = xqb[n];
  const float xn0 = qv[0], xn1 = qv[1], xn2 = qv[2];

  const int j0 = knn[row * 32 + q];
  const float4v c0 = xqb[j0];
  float a1x = xn0, a1y = xn1, a1z = xn2;  // pad row: d=0, finite
  if (q < 14) {
    const int j1 = knn[row * 32 + 16 + q];
    const float4v c1 = xqb[j1];
    a1x = c1[0]; a1y = c1[1]; a1z = c1[2];
  }
  const float d0x = c0[0] - xn0, d0y = c0[1] - xn1, d0z = c0[2] - xn2;
  const float d1x = a1x - xn0, d1y = a1y - xn1, d1z = a1z - xn2;

  float4v dfr[2][4];
#pragma unroll
  for (int mt = 0; mt < 2; ++mt)
#pragma unroll
    for (int nt = 0; nt < 4; ++nt) dfr[mt][nt] = (float4v){0.f, 0.f, 0.f, 0.f};

#pragma unroll
  for (int kt = 0; kt < 2; ++kt) {
    short8v af0, af1;
#pragma unroll
    for (int e = 0; e < 8; ++e) {
      const int c = kt * 32 + g * 8 + e;
      const float4v wlo = *(const float4v*)&w1row[c][0];
      const float4v whi = *(const float4v*)&w1row[c][4];
      float h = wlo[0] * d0x;
      h = fmaf(wlo[1], d0y, h);
      h = fmaf(wlo[2], d0z, h);
      h = fmaf(wlo[3], xn0, h);
      h = fmaf(whi[0], xn1, h);
      h = fmaf(whi[1], xn2, h);
      h = fmaf(h, whi[2], whi[3]);
      h = fmaxf(h, 0.2f * h);
      af0[e] = f2bf(h);
      float h1v = wlo[0] * d1x;
      h1v = fmaf(wlo[1], d1y, h1v);
      h1v = fmaf(wlo[2], d1z, h1v);
      h1v = fmaf(wlo[3], xn0, h1v);
      h1v = fmaf(whi[0], xn1, h1v);
      h1v = fmaf(whi[1], xn2, h1v);
      h1v = fmaf(h1v, whi[2], whi[3]);
      h1v = fmaxf(h1v, 0.2f * h1v);
      af1[e] = f2bf(h1v);
    }
#pragma unroll
    for (int nt = 0; nt < 4; ++nt) {
      dfr[0][nt] = __builtin_amdgcn_mfma_f32_16x16x32_bf16(af0, bf[kt][nt], dfr[0][nt], 0, 0, 0);
      dfr[1][nt] = __builtin_amdgcn_mfma_f32_16x16x32_bf16(af1, bf[kt][nt], dfr[1][nt], 0, 0, 0);
    }
  }

  float part[2][4];
#pragma unroll
  for (int mt = 0; mt < 2; ++mt)
#pragma unroll
    for (int r = 0; r < 4; ++r) part[mt][r] = 0.f;
#pragma unroll
  for (int mt = 0; mt < 2; ++mt)
#pragma unroll
    for (int nt = 0; nt < 4; ++nt) {
      float4v d = dfr[mt][nt];
#pragma unroll
      for (int r = 0; r < 4; ++r) {
        float h2 = fmaf(d[r], s2r[nt], be2r[nt]);
        h2 = fmaxf(h2, 0.2f * h2);
        d[r] = h2;
        part[mt][r] = fmaf(war[nt], h2, part[mt][r]);
      }
      dfr[mt][nt] = d;
    }
#pragma unroll
  for (int mt = 0; mt < 2; ++mt)
#pragma unroll
    for (int r = 0; r < 4; ++r) {
      float p = part[mt][r];
      p += __shfl_xor(p, 1, 64);
      p += __shfl_xor(p, 2, 64);
      p += __shfl_xor(p, 4, 64);
      p += __shfl_xor(p, 8, 64);
      part[mt][r] = p;
    }

  const int mrow = g * 4;
  float sc0[4], sc1[4];
  float mloc = -3.0e38f;
#pragma unroll
  for (int r = 0; r < 4; ++r) {
    float a = fmaf(part[0][r] + ba0, sa, bga0);
    a = fmaxf(a, 0.2f * a);
    sc0[r] = a;
    mloc = fmaxf(mloc, a);
  }
#pragma unroll
  for (int r = 0; r < 4; ++r) {
    float a = fmaf(part[1][r] + ba0, sa, bga0);
    a = fmaxf(a, 0.2f * a);
    sc1[r] = a;
    if (mrow + r < 14) mloc = fmaxf(mloc, a);
  }
  mloc = fmaxf(mloc, __shfl_xor(mloc, 16, 64));
  mloc = fmaxf(mloc, __shfl_xor(mloc, 32, 64));

  float e0[4], e1[4];
  float l10 = 0.f, l20 = 0.f, l30 = 0.f;
#pragma unroll
  for (int r = 0; r < 4; ++r) {
    const float vv = expf(sc0[r] - mloc);
    e0[r] = vv;
    l30 += vv;
    l20 += vv;
    if (mrow + r < 10) l10 += vv;
  }
#pragma unroll
  for (int r = 0; r < 4; ++r) {
    const float vv = (mrow + r < 14) ? expf(sc1[r] - mloc) : 0.f;
    e1[r] = vv;
    l30 += vv;
    if (mrow + r < 4) l20 += vv;
  }
  l10 += __shfl_xor(l10, 16, 64); l10 += __shfl_xor(l10, 32, 64);
  l20 += __shfl_xor(l20, 16, 64); l20 += __shfl_xor(l20, 32, 64);
  l30 += __shfl_xor(l30, 16, 64); l30 += __shfl_xor(l30, 32, 64);
  const float i10 = 1.0f / l10, i20 = 1.0f / l20, i30 = 1.0f / l30;
  const float third = 1.0f / 3.0f;

  float wgt0[4], wgt1[4];
#pragma unroll
  for (int r = 0; r < 4; ++r) {
    wgt0[r] = e0[r] * (((mrow + r < 10) ? i10 : 0.f) + i20 + i30) * third;
    wgt1[r] = e1[r] * (((mrow + r < 4) ? i20 : 0.f) + i30) * third;
  }

  float acc[4] = {0.f, 0.f, 0.f, 0.f};
#pragma unroll
  for (int nt = 0; nt < 4; ++nt) {
#pragma unroll
    for (int r = 0; r < 4; ++r) {
      acc[nt] = fmaf(wgt0[r], dfr[0][nt][r], acc[nt]);
      acc[nt] = fmaf(wgt1[r], dfr[1][nt][r], acc[nt]);
    }
  }
#pragma unroll
  for (int nt = 0; nt < 4; ++nt) {
    acc[nt] += __shfl_xor(acc[nt], 16, 64);
    acc[nt] += __shfl_xor(acc[nt], 32, 64);
  }
  const float val = (g == 0) ? acc[0] : (g == 1) ? acc[1] : (g == 2) ? acc[2] : acc[3];
  out[(size_t)(b * 64 + q + 16 * g) * NPT + n] = val;
}

extern "C" void kernel_launch(void* const* d_in, const int* in_sizes, int n_in,
                              void* d_out, int out_size, void* d_ws, size_t ws_size,
                              hipStream_t stream) {
  const float* x = (const float*)d_in[0];
  const float* w1 = (const float*)d_in[1];
  const float* g1 = (const float*)d_in[2];
  const float* b1 = (const float*)d_in[3];
  const float* w2 = (const float*)d_in[4];
  const float* g2 = (const float*)d_in[5];
  const float* b2 = (const float*)d_in[6];
  const float* wa = (const float*)d_in[7];
  const float* ba = (const float*)d_in[8];
  const float* ga = (const float*)d_in[9];
  const float* bga = (const float*)d_in[10];
  float* out = (float*)d_out;

  float4v* xq = (float4v*)d_ws;                         // 512 KB
  int* knn = (int*)((char*)d_ws + ROWS * 16);           // 4 MB
  short8v* w2bf = (short8v*)((char*)d_ws + ROWS * 16 + ROWS * 32 * 4);  // 8 KB

  prep_kernel<<<dim3(ROWS / 256 + 1), dim3(256), 0, stream>>>(x, w2, xq, w2bf);
  knn_kernel<<<dim3(ROWS / (4 * QW)), dim3(256), 0, stream>>>(xq, knn);
  pcc_mlp_mfma<<<dim3(ROWS / 4), dim3(256), 0, stream>>>(
      xq, w1, g1, b1, w2bf, g2, b2, wa, ba, ga, bga, knn, out);
}

// Round 6
// 135.527 us; speedup vs baseline: 3.1010x; 1.0835x over previous
//
#include <hip/hip_runtime.h>
#include <math.h>

// PCCNet: KNN(30) + per-neighbor MLP(6->64->64) + 3-scale prefix softmax attention.
// Round 6: knn 4x-unrolled batched loads (ILP); mlp pre-scaled layer-1 weights
// (center term hoisted, shared by both rows) + v_cvt_pk_bf16_f32 packing.

#define NB 8
#define NPT 4096
#define KMAXK 30
#define ROWS (NB * NPT)
#define QW 4     // queries per wave
#define SCAP 96  // survivor cap per query (observed ~48)

typedef __attribute__((ext_vector_type(8))) short short8v;
typedef __attribute__((ext_vector_type(4))) float float4v;
typedef __attribute__((ext_vector_type(2))) float float2v;
typedef __attribute__((ext_vector_type(4))) int int4v;

__device__ __forceinline__ unsigned long long shflx64(unsigned long long v, int m) {
  unsigned lo = (unsigned)__shfl_xor((int)(unsigned)(v & 0xFFFFFFFFull), m, 64);
  unsigned hi = (unsigned)__shfl_xor((int)(unsigned)(v >> 32), m, 64);
  return ((unsigned long long)hi << 32) | (unsigned long long)lo;
}

__device__ __forceinline__ short f2bf(float x) {  // f32 -> bf16 RNE
  unsigned u = __float_as_uint(x);
  return (short)((u + 0x7FFFu + ((u >> 16) & 1u)) >> 16);
}

__device__ __forceinline__ int cvtpk(float lo, float hi) {  // packed bf16 RNE
  int r;
  asm("v_cvt_pk_bf16_f32 %0, %1, %2" : "=v"(r) : "v"(lo), "v"(hi));
  return r;
}

__device__ __forceinline__ unsigned ordkey(float f) {  // monotonic u32 of f32
  const unsigned bits = __float_as_uint(f);
  return bits ^ ((unsigned)((int)bits >> 31) | 0x80000000u);
}

__device__ __forceinline__ float sbcast(float v) {  // force wave-uniform -> SGPR
  return __int_as_float(__builtin_amdgcn_readfirstlane(__float_as_int(v)));
}

// ---------------- Kernel 0: pack (x,y,z,|x|^2) + pack W2 bf16 fragments ----
__global__ __launch_bounds__(256) void prep_kernel(const float* __restrict__ x,
                                                   const float* __restrict__ w2,
                                                   float4v* __restrict__ xq,
                                                   short8v* __restrict__ w2bf) {
  const int i = blockIdx.x * 256 + threadIdx.x;
  if (i < ROWS) {
    const int b = i >> 12, m = i & (NPT - 1);
    const float* xb = x + (size_t)b * 3 * NPT;
    const float y0 = xb[m], y1 = xb[NPT + m], y2 = xb[2 * NPT + m];
    const float xx = y0 * y0 + y1 * y1 + y2 * y2;
    xq[i] = (float4v){y0, y1, y2, xx};
  }
  if (blockIdx.x == ROWS / 256) {
    // 512 fragment vectors: v = (kt*4+nt)*64 + lane; elem e = w2[nt*16+q][kt*32+g*8+e]
#pragma unroll
    for (int u = 0; u < 2; ++u) {
      const int v = threadIdx.x * 2 + u;
      const int lane = v & 63, fi = v >> 6;
      const int kt = fi >> 2, nt = fi & 3;
      const int q = lane & 15, g = lane >> 4;
      const float* src = w2 + (nt * 16 + q) * 64 + kt * 32 + g * 8;
      short8v tt;
#pragma unroll
      for (int e = 0; e < 8; ++e) tt[e] = f2bf(src[e]);
      w2bf[v] = tt;
    }
  }
}

// ---------------- Kernel 1: exact top-30 neighbor indices, 4 queries/wave --
// 4x-unrolled candidate loop: 4 float4 loads issued back-to-back (fixed-stride
// immediate offsets) so L1 latency overlaps the pk-f32 distance math.
__global__ __launch_bounds__(256, 6) void knn_kernel(const float4v* __restrict__ xq,
                                                     int* __restrict__ knn) {
  __shared__ unsigned long long buf[4][QW][SCAP];  // 12 KB
  const int wv = threadIdx.x >> 6;
  const int lane = threadIdx.x & 63;
  const int row0 = ((blockIdx.x << 2) + wv) * QW;  // 4 consecutive points, same batch
  const int b = row0 >> 12;
  const int n0 = row0 & (NPT - 1);
  const float4v* xqb = xq + ((size_t)b << 12);
  const float4v* pc = xqb + lane;

  // wave-uniform query constants
  float qx[QW], qy[QW], qz[QW], qq[QW];
#pragma unroll
  for (int qi = 0; qi < QW; ++qi) {
    const float4v qv = xqb[n0 + qi];
    qx[qi] = sbcast(qv[0]);
    qy[qi] = sbcast(qv[1]);
    qz[qi] = sbcast(qv[2]);
    qq[qi] = sbcast(qv[3]);
  }
  float2v qxp[2], qyp[2], qzp[2], qqp[2];
#pragma unroll
  for (int p = 0; p < 2; ++p) {
    qxp[p] = (float2v){qx[2 * p], qx[2 * p + 1]};
    qyp[p] = (float2v){qy[2 * p], qy[2 * p + 1]};
    qzp[p] = (float2v){qz[2 * p], qz[2 * p + 1]};
    qqp[p] = (float2v){qq[2 * p], qq[2 * p + 1]};
  }

  // ---- pass 1: per-query lane-max, unrolled x4 ----
  float2v kmaxp[2];
  kmaxp[0] = (float2v){-3.0e38f, -3.0e38f};
  kmaxp[1] = (float2v){-3.0e38f, -3.0e38f};
  for (int j = 0; j < 64; j += 4) {
    float4v cL[4];
#pragma unroll
    for (int u = 0; u < 4; ++u) cL[u] = pc[(size_t)(j + u) << 6];
#pragma unroll
    for (int u = 0; u < 4; ++u) {
      const float4v c = cL[u];
      const float2v cx = (float2v){c[0], c[0]};
      const float2v cy = (float2v){c[1], c[1]};
      const float2v cz = (float2v){c[2], c[2]};
      const float2v cw = (float2v){c[3], c[3]};
#pragma unroll
      for (int p = 0; p < 2; ++p) {
        float2v inner = cx * qxp[p];
        inner = __builtin_elementwise_fma(cy, qyp[p], inner);
        inner = __builtin_elementwise_fma(cz, qzp[p], inner);
        const float2v pd = (inner + inner) - qqp[p] - cw;
        kmaxp[p] = __builtin_elementwise_max(kmaxp[p], pd);
      }
    }
  }
  const float kmaxs[QW] = {kmaxp[0][0], kmaxp[0][1], kmaxp[1][0], kmaxp[1][1]};

  // per-query threshold: 30th largest of the 64 lane-maxima, minus eps slack
  float thr[QW];
#pragma unroll
  for (int qi = 0; qi < QW; ++qi) {
    float v = kmaxs[qi];
#pragma unroll
    for (int kk = 2; kk <= 64; kk <<= 1) {
#pragma unroll
      for (int jj = 32; jj >= 1; jj >>= 1) {
        if (jj < kk) {
          const float o = __shfl_xor(v, jj, 64);
          const bool up = ((lane & kk) == 0);
          const bool takeMax = (((lane & jj) != 0) == up);
          v = takeMax ? fmaxf(v, o) : fminf(v, o);
        }
      }
    }
    thr[qi] = sbcast(__shfl(v, 34, 64)) - 1.0e-4f;  // eps: survivor superset only
  }

  // ---- pass 2: recompute + ballot-compact, unrolled x4 ----
  int cnt[QW];
#pragma unroll
  for (int qi = 0; qi < QW; ++qi) cnt[qi] = 0;
  for (int j = 0; j < 64; j += 4) {
    float4v cL[4];
#pragma unroll
    for (int u = 0; u < 4; ++u) cL[u] = pc[(size_t)(j + u) << 6];
    float2v pdp[4][2];
#pragma unroll
    for (int u = 0; u < 4; ++u) {
      const float4v c = cL[u];
      const float2v cx = (float2v){c[0], c[0]};
      const float2v cy = (float2v){c[1], c[1]};
      const float2v cz = (float2v){c[2], c[2]};
      const float2v cw = (float2v){c[3], c[3]};
#pragma unroll
      for (int p = 0; p < 2; ++p) {
        float2v inner = cx * qxp[p];
        inner = __builtin_elementwise_fma(cy, qyp[p], inner);
        inner = __builtin_elementwise_fma(cz, qzp[p], inner);
        pdp[u][p] = (inner + inner) - qqp[p] - cw;
      }
    }
#pragma unroll
    for (int u = 0; u < 4; ++u) {
      const int m = ((j + u) << 6) + lane;
#pragma unroll
      for (int qi = 0; qi < QW; ++qi) {
        const float pd = pdp[u][qi >> 1][qi & 1];
        const bool pred = pd >= thr[qi];
        const unsigned long long mask = __ballot(pred);
        if (pred) {
          const int pos = cnt[qi] + (int)__popcll(mask & ((1ull << lane) - 1ull));
          if (pos < SCAP) {
            buf[wv][qi][pos] = ((unsigned long long)ordkey(pd) << 32) | (unsigned)(4095 - m);
          }
        }
        cnt[qi] += (int)__popcll(mask);
      }
    }
  }

  // ---- selection per query ----
#pragma unroll 1
  for (int qi = 0; qi < QW; ++qi) {
    const int c = cnt[qi];
    const int outbase = (row0 + qi) * 32;
    if (c >= KMAXK && c <= 64) {
      // typical: 64-lane bitonic sort ascending of packed (key, 4095-m)
      unsigned long long val = (lane < c) ? buf[wv][qi][lane] : 0ull;
#pragma unroll
      for (int kk = 2; kk <= 64; kk <<= 1) {
#pragma unroll
        for (int jj = 32; jj >= 1; jj >>= 1) {
          if (jj < kk) {
            const unsigned long long o = shflx64(val, jj);
            const bool up = ((lane & kk) == 0);
            const bool takeMax = (((lane & jj) != 0) == up);
            const unsigned long long mx = val > o ? val : o;
            const unsigned long long mn = val > o ? o : val;
            val = takeMax ? mx : mn;
          }
        }
      }
      const int rank = 63 - lane;
      if (rank < KMAXK) {
        const int m = 4095 - (int)(val & 0xFFFFFFFFull);
        knn[outbase + rank] = m;
      }
    } else if (c > 64 && c <= SCAP) {
      // uncommon: iterative wave-argmax over LDS survivors
      for (int r = 0; r < KMAXK; ++r) {
        unsigned long long lmax = 0ull;
        int lpos = -1;
        for (int p = lane; p < c; p += 64) {
          const unsigned long long q2 = buf[wv][qi][p];
          if (q2 > lmax) { lmax = q2; lpos = p; }
        }
        unsigned long long g = lmax;
#pragma unroll
        for (int s = 32; s >= 1; s >>= 1) {
          const unsigned long long o = shflx64(g, s);
          g = o > g ? o : g;
        }
        const unsigned long long pm = __ballot(lmax == g && lpos >= 0);
        const int lowlane = (int)(__ffsll((unsigned long long)pm) - 1);
        if (lane == lowlane) buf[wv][qi][lpos] = 0ull;
        if (lane == 0) knn[outbase + r] = 4095 - (int)(g & 0xFFFFFFFFull);
      }
    } else {
      // pathological (never expected): exact scan-select from global, 30 rounds
      unsigned long long prev = ~0ull;
      for (int r = 0; r < KMAXK; ++r) {
        unsigned long long best = 0ull;
        for (int j = 0; j < 64; ++j) {
          const int m = (j << 6) + lane;
          const float4v cc = xqb[m];
          float inner = cc[0] * qx[qi];
          inner = fmaf(cc[1], qy[qi], inner);
          inner = fmaf(cc[2], qz[qi], inner);
          const float pd = 2.0f * inner - qq[qi] - cc[3];
          const unsigned long long key =
              ((unsigned long long)ordkey(pd) << 32) | (unsigned)(4095 - m);
          if (key < prev && key > best) best = key;
        }
#pragma unroll
        for (int s = 32; s >= 1; s >>= 1) {
          const unsigned long long o = shflx64(best, s);
          best = o > best ? o : best;
        }
        if (lane == 0) knn[outbase + r] = 4095 - (int)(best & 0xFFFFFFFFull);
        prev = best;
      }
    }
  }
}

// ---------------- Kernel 2: MFMA MLP + 3-scale softmax attention -----------
// One wave per point. Layer-1 via pre-scaled weights: h1 = (W1d*s1).d + hcb
// where hcb = (W1c*s1).center + be1 is shared by both neighbor rows.
// A = h1 (32 rows: 30 neighbors + 2 pad), B = W2^T (pre-packed bf16 frags).
// C/D: n = lane&15, m = (lane>>4)*4+reg.
__global__ __launch_bounds__(256) void pcc_mlp_mfma(
    const float4v* __restrict__ xq, const float* __restrict__ w1,
    const float* __restrict__ g1, const float* __restrict__ b1,
    const short8v* __restrict__ w2bf, const float* __restrict__ g2,
    const float* __restrict__ b2, const float* __restrict__ wa,
    const float* __restrict__ ba, const float* __restrict__ ga,
    const float* __restrict__ bga, const int* __restrict__ knn,
    float* __restrict__ out) {
  __shared__ float w1s[64][8];  // per ch: w1d*s1 (3), w1c*s1 (3), be1, 0  (2 KB)
  const int tid = threadIdx.x;
  const float invs = 1.0f / sqrtf(1.0f + 1e-5f);
  for (int idx = tid; idx < 512; idx += 256) {
    const int c = idx >> 3, s = idx & 7;
    float v = 0.f;
    if (s < 6) v = w1[c * 6 + s] * (g1[c] * invs);
    else if (s == 6) v = b1[c];
    w1s[c][s] = v;
  }
  __syncthreads();

  const int wv = tid >> 6, lane = tid & 63;
  const int q = lane & 15, g = lane >> 4;
  const int row = (blockIdx.x << 2) + wv;
  const int b = row >> 12, n = row & (NPT - 1);
  const float4v* xqb = xq + ((size_t)b << 12);

  const float4v qv = xqb[n];
  const float xn0 = qv[0], xn1 = qv[1], xn2 = qv[2];

  const int j0 = knn[row * 32 + q];
  const float4v c0 = xqb[j0];
  float a1x = xn0, a1y = xn1, a1z = xn2;  // pad row: d=0, finite
  if (q < 14) {
    const int j1 = knn[row * 32 + 16 + q];
    const float4v c1 = xqb[j1];
    a1x = c1[0]; a1y = c1[1]; a1z = c1[2];
  }
  const float d0x = c0[0] - xn0, d0y = c0[1] - xn1, d0z = c0[2] - xn2;
  const float d1x = a1x - xn0, d1y = a1y - xn1, d1z = a1z - xn2;

  float4v dfr[2][4];
#pragma unroll
  for (int mt = 0; mt < 2; ++mt)
#pragma unroll
    for (int nt = 0; nt < 4; ++nt) dfr[mt][nt] = (float4v){0.f, 0.f, 0.f, 0.f};

#pragma unroll
  for (int kt = 0; kt < 2; ++kt) {
    short8v bfk[4];
#pragma unroll
    for (int nt = 0; nt < 4; ++nt) bfk[nt] = w2bf[((kt << 2) + nt) * 64 + lane];
    float h0[8], h1r[8];
#pragma unroll
    for (int e = 0; e < 8; ++e) {
      const int c = kt * 32 + g * 8 + e;
      const float4v wlo = *(const float4v*)&w1s[c][0];
      const float4v whi = *(const float4v*)&w1s[c][4];
      const float hcb = fmaf(wlo[3], xn0, fmaf(whi[0], xn1, fmaf(whi[1], xn2, whi[2])));
      float h = fmaf(wlo[0], d0x, fmaf(wlo[1], d0y, fmaf(wlo[2], d0z, hcb)));
      h0[e] = fmaxf(h, 0.2f * h);
      float hb = fmaf(wlo[0], d1x, fmaf(wlo[1], d1y, fmaf(wlo[2], d1z, hcb)));
      h1r[e] = fmaxf(hb, 0.2f * hb);
    }
    int4v a0i, a1i;
#pragma unroll
    for (int e = 0; e < 4; ++e) {
      a0i[e] = cvtpk(h0[2 * e], h0[2 * e + 1]);
      a1i[e] = cvtpk(h1r[2 * e], h1r[2 * e + 1]);
    }
    const short8v af0 = __builtin_bit_cast(short8v, a0i);
    const short8v af1 = __builtin_bit_cast(short8v, a1i);
#pragma unroll
    for (int nt = 0; nt < 4; ++nt) {
      dfr[0][nt] = __builtin_amdgcn_mfma_f32_16x16x32_bf16(af0, bfk[nt], dfr[0][nt], 0, 0, 0);
      dfr[1][nt] = __builtin_amdgcn_mfma_f32_16x16x32_bf16(af1, bfk[nt], dfr[1][nt], 0, 0, 0);
    }
  }

  float s2r[4], be2r[4], war[4];
#pragma unroll
  for (int nt = 0; nt < 4; ++nt) {
    s2r[nt] = g2[q + 16 * nt] * invs;
    be2r[nt] = b2[q + 16 * nt];
    war[nt] = wa[q + 16 * nt];
  }
  const float sa = ga[0] * invs, ba0 = ba[0], bga0 = bga[0];

  float part[2][4];
#pragma unroll
  for (int mt = 0; mt < 2; ++mt)
#pragma unroll
    for (int r = 0; r < 4; ++r) part[mt][r] = 0.f;
#pragma unroll
  for (int mt = 0; mt < 2; ++mt)
#pragma unroll
    for (int nt = 0; nt < 4; ++nt) {
      float4v d = dfr[mt][nt];
#pragma unroll
      for (int r = 0; r < 4; ++r) {
        float h2 = fmaf(d[r], s2r[nt], be2r[nt]);
        h2 = fmaxf(h2, 0.2f * h2);
        d[r] = h2;
        part[mt][r] = fmaf(war[nt], h2, part[mt][r]);
      }
      dfr[mt][nt] = d;
    }
#pragma unroll
  for (int mt = 0; mt < 2; ++mt)
#pragma unroll
    for (int r = 0; r < 4; ++r) {
      float p = part[mt][r];
      p += __shfl_xor(p, 1, 64);
      p += __shfl_xor(p, 2, 64);
      p += __shfl_xor(p, 4, 64);
      p += __shfl_xor(p, 8, 64);
      part[mt][r] = p;
    }

  const int mrow = g * 4;
  float sc0[4], sc1[4];
  float mloc = -3.0e38f;
#pragma unroll
  for (int r = 0; r < 4; ++r) {
    float a = fmaf(part[0][r] + ba0, sa, bga0);
    a = fmaxf(a, 0.2f * a);
    sc0[r] = a;
    mloc = fmaxf(mloc, a);
  }
#pragma unroll
  for (int r = 0; r < 4; ++r) {
    float a = fmaf(part[1][r] + ba0, sa, bga0);
    a = fmaxf(a, 0.2f * a);
    sc1[r] = a;
    if (mrow + r < 14) mloc = fmaxf(mloc, a);
  }
  mloc = fmaxf(mloc, __shfl_xor(mloc, 16, 64));
  mloc = fmaxf(mloc, __shfl_xor(mloc, 32, 64));

  float e0[4], e1[4];
  float l10 = 0.f, l20 = 0.f, l30 = 0.f;
#pragma unroll
  for (int r = 0; r < 4; ++r) {
    const float vv = expf(sc0[r] - mloc);
    e0[r] = vv;
    l30 += vv;
    l20 += vv;
    if (mrow + r < 10) l10 += vv;
  }
#pragma unroll
  for (int r = 0; r < 4; ++r) {
    const float vv = (mrow + r < 14) ? expf(sc1[r] - mloc) : 0.f;
    e1[r] = vv;
    l30 += vv;
    if (mrow + r < 4) l20 += vv;
  }
  l10 += __shfl_xor(l10, 16, 64); l10 += __shfl_xor(l10, 32, 64);
  l20 += __shfl_xor(l20, 16, 64); l20 += __shfl_xor(l20, 32, 64);
  l30 += __shfl_xor(l30, 16, 64); l30 += __shfl_xor(l30, 32, 64);
  const float i10 = 1.0f / l10, i20 = 1.0f / l20, i30 = 1.0f / l30;
  const float third = 1.0f / 3.0f;

  float wgt0[4], wgt1[4];
#pragma unroll
  for (int r = 0; r < 4; ++r) {
    wgt0[r] = e0[r] * (((mrow + r < 10) ? i10 : 0.f) + i20 + i30) * third;
    wgt1[r] = e1[r] * (((mrow + r < 4) ? i20 : 0.f) + i30) * third;
  }

  float acc[4] = {0.f, 0.f, 0.f, 0.f};
#pragma unroll
  for (int nt = 0; nt < 4; ++nt) {
#pragma unroll
    for (int r = 0; r < 4; ++r) {
      acc[nt] = fmaf(wgt0[r], dfr[0][nt][r], acc[nt]);
      acc[nt] = fmaf(wgt1[r], dfr[1][nt][r], acc[nt]);
    }
  }
#pragma unroll
  for (int nt = 0; nt < 4; ++nt) {
    acc[nt] += __shfl_xor(acc[nt], 16, 64);
    acc[nt] += __shfl_xor(acc[nt], 32, 64);
  }
  const float val = (g == 0) ? acc[0] : (g == 1) ? acc[1] : (g == 2) ? acc[2] : acc[3];
  out[(size_t)(b * 64 + q + 16 * g) * NPT + n] = val;
}

extern "C" void kernel_launch(void* const* d_in, const int* in_sizes, int n_in,
                              void* d_out, int out_size, void* d_ws, size_t ws_size,
                              hipStream_t stream) {
  const float* x = (const float*)d_in[0];
  const float* w1 = (const float*)d_in[1];
  const float* g1 = (const float*)d_in[2];
  const float* b1 = (const float*)d_in[3];
  const float* w2 = (const float*)d_in[4];
  const float* g2 = (const float*)d_in[5];
  const float* b2 = (const float*)d_in[6];
  const float* wa = (const float*)d_in[7];
  const float* ba = (const float*)d_in[8];
  const float* ga = (const float*)d_in[9];
  const float* bga = (const float*)d_in[10];
  float* out = (float*)d_out;

  float4v* xq = (float4v*)d_ws;                         // 512 KB
  int* knn = (int*)((char*)d_ws + ROWS * 16);           // 4 MB
  short8v* w2bf = (short8v*)((char*)d_ws + ROWS * 16 + ROWS * 32 * 4);  // 8 KB

  prep_kernel<<<dim3(ROWS / 256 + 1), dim3(256), 0, stream>>>(x, w2, xq, w2bf);
  knn_kernel<<<dim3(ROWS / (4 * QW)), dim3(256), 0, stream>>>(xq, knn);
  pcc_mlp_mfma<<<dim3(ROWS / 4), dim3(256), 0, stream>>>(
      xq, w1, g1, b1, w2bf, g2, b2, wa, ba, ga, bga, knn, out);
}